// Round 5
// baseline (1660.256 us; speedup 1.0000x reference)
//
#include <hip/hip_runtime.h>

#define N_NODES 100000
#define D 64
#define SCAN_CHUNK 256
#define NBLK_SCAN ((N_NODES + SCAN_CHUNK - 1) / SCAN_CHUNK)  // 391

__device__ __forceinline__ unsigned f2bf(float f) {  // RNE float->bf16 bits
  unsigned u = __float_as_uint(f);
  return (u + 0x7fffu + ((u >> 16) & 1u)) >> 16;
}
#define BF_LO(u) __uint_as_float(((unsigned)(u)) << 16)
#define BF_HI(u) __uint_as_float(((unsigned)(u)) & 0xffff0000u)

// ---------- bf16-ize feature table (8 floats / thread) ----------
__global__ void to_bf16_kernel(const float4* __restrict__ in,
                               uint4* __restrict__ outp, int n8) {
  int i = blockIdx.x * blockDim.x + threadIdx.x;
  int stride = gridDim.x * blockDim.x;
  for (; i < n8; i += stride) {
    float4 a = in[2 * i], b = in[2 * i + 1];
    uint4 r;
    r.x = f2bf(a.x) | (f2bf(a.y) << 16);
    r.y = f2bf(a.z) | (f2bf(a.w) << 16);
    r.z = f2bf(b.x) | (f2bf(b.y) << 16);
    r.w = f2bf(b.z) | (f2bf(b.w) << 16);
    outp[i] = r;
  }
}

// ---------- CSR build ----------
__global__ void hist_kernel(const int* __restrict__ dst, int* __restrict__ degI,
                            int nE) {
  int i = blockIdx.x * blockDim.x + threadIdx.x;
  int stride = gridDim.x * blockDim.x;
  for (int e = i; e < nE; e += stride) atomicAdd(&degI[dst[e]], 1);
}

__global__ void scan_p1(const int* __restrict__ degI, int* __restrict__ bsum) {
  int t = threadIdx.x, b = blockIdx.x;
  int i = b * SCAN_CHUNK + t;
  int v = (i < N_NODES) ? degI[i] : 0;
  for (int off = 32; off; off >>= 1) v += __shfl_down(v, off);
  __shared__ int ws4[4];
  if ((t & 63) == 0) ws4[t >> 6] = v;
  __syncthreads();
  if (t == 0) bsum[b] = ws4[0] + ws4[1] + ws4[2] + ws4[3];
}

__global__ void scan_p2(int* __restrict__ bsum, int nB) {
  __shared__ int s[512];
  int t = threadIdx.x;
  int orig = (t < nB) ? bsum[t] : 0;
  s[t] = orig;
  __syncthreads();
  for (int off = 1; off < 512; off <<= 1) {
    int v = (t >= off) ? s[t - off] : 0;
    __syncthreads();
    s[t] += v;
    __syncthreads();
  }
  if (t < nB) bsum[t] = s[t] - orig;
}

__global__ void scan_p3(const int* __restrict__ degI, const int* __restrict__ bsum,
                        int* __restrict__ rowstart, int* __restrict__ cursor) {
  __shared__ int s[SCAN_CHUNK];
  int t = threadIdx.x, b = blockIdx.x;
  int i = b * SCAN_CHUNK + t;
  int d = (i < N_NODES) ? degI[i] : 0;
  s[t] = d;
  __syncthreads();
  for (int off = 1; off < SCAN_CHUNK; off <<= 1) {
    int v = (t >= off) ? s[t - off] : 0;
    __syncthreads();
    s[t] += v;
    __syncthreads();
  }
  if (i < N_NODES) {
    int ex = s[t] - d + bsum[b];
    rowstart[i] = ex;
    cursor[i] = ex;
  }
}

__global__ void build_adj_kernel(const int* __restrict__ src,
                                 const int* __restrict__ dst,
                                 int* __restrict__ cursor, int* __restrict__ adj,
                                 int nE) {
  int i = blockIdx.x * blockDim.x + threadIdx.x;
  int stride = gridDim.x * blockDim.x;
  for (int e = i; e < nE; e += stride) {
    int d = dst[e];
    int p = atomicAdd(&cursor[d], 1);
    adj[p] = src[e];
  }
}

// ---------- Fused SAGE layer v4 (bf16 gather, 4-deep MLP, no spills) ----------
// Wave-per-node. lane = o*8 + j8 : o = edge slot (gather) / k-range (GEMV),
// j8 = 16B feature chunk (8 bf16). Gather: 8 edges per wave-load, 32 edges
// (4 independent loads) per inner iteration. GEMV: lane owns outputs
// 8*j8..+7 over k in [8o,8o+8); W bf16 in LDS (160B-padded rows).

#define ACC8(v, m)                          \
  acc[0] = fmaf(BF_LO(v.x), m, acc[0]);     \
  acc[1] = fmaf(BF_HI(v.x), m, acc[1]);     \
  acc[2] = fmaf(BF_LO(v.y), m, acc[2]);     \
  acc[3] = fmaf(BF_HI(v.y), m, acc[3]);     \
  acc[4] = fmaf(BF_LO(v.z), m, acc[4]);     \
  acc[5] = fmaf(BF_HI(v.z), m, acc[5]);     \
  acc[6] = fmaf(BF_LO(v.w), m, acc[6]);     \
  acc[7] = fmaf(BF_HI(v.w), m, acc[7]);

__global__ __launch_bounds__(256, 4) void sage_fused_v4(
    const int* __restrict__ rowstart, const int* __restrict__ degI,
    const int* __restrict__ adj,
    const float* __restrict__ selfF,           // f32 self features (mode 0)
    const unsigned short* __restrict__ selfB,  // bf16 self features (mode 1)
    const unsigned short* __restrict__ gatB,   // bf16 gather table
    const float* __restrict__ Wl, const float* __restrict__ bl,
    const float* __restrict__ Wr, const float* __restrict__ Wc,
    const float* __restrict__ bc,
    float* __restrict__ outF, unsigned short* __restrict__ outB,
    int nE, int mode) {
  __shared__ unsigned short WT[2][64 * 80];  // [mat][k*80 + j], 160B rows
  int tid = threadIdx.x;
  for (int i = tid; i < 4096; i += 256) {
    int k = i >> 6, j = i & 63;
    WT[0][k * 80 + j] = (unsigned short)f2bf(Wl[j * 64 + k]);
    WT[1][k * 80 + j] = (unsigned short)f2bf(Wr[j * 64 + k]);
  }
  __syncthreads();

  int lane = tid & 63;
  int o = lane >> 3, j8 = lane & 7;
  float blv[8];
  {
    float4 b0 = ((const float4*)bl)[2 * j8], b1 = ((const float4*)bl)[2 * j8 + 1];
    blv[0] = b0.x; blv[1] = b0.y; blv[2] = b0.z; blv[3] = b0.w;
    blv[4] = b1.x; blv[5] = b1.y; blv[6] = b1.z; blv[7] = b1.w;
  }

  int gw = (blockIdx.x * 256 + tid) >> 6;
  int nWaves = (gridDim.x * 256) >> 6;

  for (int n = gw; n < N_NODES; n += nWaves) {
    int rs = rowstart[n], dg = degI[n];
    float acc[8] = {0.f, 0.f, 0.f, 0.f, 0.f, 0.f, 0.f, 0.f};
    for (int base = 0; base < dg; base += 64) {
      int cnt = min(dg - base, 64);
      int a = adj[min(rs + base + lane, nE - 1)];
      for (int t = 0; t < cnt; t += 32) {
        int el0 = t + o, el1 = t + 8 + o, el2 = t + 16 + o, el3 = t + 24 + o;
        int nb0 = __shfl(a, el0), nb1 = __shfl(a, el1);
        int nb2 = __shfl(a, el2), nb3 = __shfl(a, el3);
        bool ok0 = el0 < cnt, ok1 = el1 < cnt, ok2 = el2 < cnt, ok3 = el3 < cnt;
        nb0 = ok0 ? nb0 : n; nb1 = ok1 ? nb1 : n;
        nb2 = ok2 ? nb2 : n; nb3 = ok3 ? nb3 : n;
        uint4 v0 = *(const uint4*)(gatB + (size_t)nb0 * 64 + j8 * 8);
        uint4 v1 = *(const uint4*)(gatB + (size_t)nb1 * 64 + j8 * 8);
        uint4 v2 = *(const uint4*)(gatB + (size_t)nb2 * 64 + j8 * 8);
        uint4 v3 = *(const uint4*)(gatB + (size_t)nb3 * 64 + j8 * 8);
        float m0 = ok0 ? 1.f : 0.f, m1 = ok1 ? 1.f : 0.f;
        float m2 = ok2 ? 1.f : 0.f, m3 = ok3 ? 1.f : 0.f;
        ACC8(v0, m0)
        ACC8(v1, m1)
        ACC8(v2, m2)
        ACC8(v3, m3)
      }
    }
    // reduce partial sums across the 8 edge-slots (lane bits 3,4,5)
#pragma unroll
    for (int jj = 0; jj < 8; ++jj) {
      acc[jj] += __shfl_xor(acc[jj], 8);
      acc[jj] += __shfl_xor(acc[jj], 16);
      acc[jj] += __shfl_xor(acc[jj], 32);
    }
    float inv = 1.f / (float)max(dg, 1);
#pragma unroll
    for (int jj = 0; jj < 8; ++jj) acc[jj] *= inv;  // acc = mean chunk j8

    // self features, chunk j8
    float xs[8];
    if (mode == 0) {
      const float4* sf = (const float4*)selfF;
      float4 a0 = sf[(size_t)n * 16 + 2 * j8], a1 = sf[(size_t)n * 16 + 2 * j8 + 1];
      xs[0] = a0.x; xs[1] = a0.y; xs[2] = a0.z; xs[3] = a0.w;
      xs[4] = a1.x; xs[5] = a1.y; xs[6] = a1.z; xs[7] = a1.w;
    } else {
      uint4 v = *(const uint4*)(selfB + (size_t)n * 64 + j8 * 8);
      xs[0] = BF_LO(v.x); xs[1] = BF_HI(v.x);
      xs[2] = BF_LO(v.y); xs[3] = BF_HI(v.y);
      xs[4] = BF_LO(v.z); xs[5] = BF_HI(v.z);
      xs[6] = BF_LO(v.w); xs[7] = BF_HI(v.w);
    }

    // dual GEMV: lane (o,j8) -> outputs 8*j8..+7 over k in [8o, 8o+8)
    float ov[8] = {0.f, 0.f, 0.f, 0.f, 0.f, 0.f, 0.f, 0.f};
    const unsigned short* wlp = &WT[0][0] + (o * 8) * 80 + j8 * 8;
    const unsigned short* wrp = &WT[1][0] + (o * 8) * 80 + j8 * 8;
#pragma unroll
    for (int i = 0; i < 8; ++i) {
      uint4 wl = *(const uint4*)(wlp + i * 80);
      uint4 wr = *(const uint4*)(wrp + i * 80);
      float mk = __shfl(acc[i], o);  // mean[8o+i] lives in lane o, comp i
      float xk = __shfl(xs[i], o);
      ov[0] = fmaf(mk, BF_LO(wl.x), fmaf(xk, BF_LO(wr.x), ov[0]));
      ov[1] = fmaf(mk, BF_HI(wl.x), fmaf(xk, BF_HI(wr.x), ov[1]));
      ov[2] = fmaf(mk, BF_LO(wl.y), fmaf(xk, BF_LO(wr.y), ov[2]));
      ov[3] = fmaf(mk, BF_HI(wl.y), fmaf(xk, BF_HI(wr.y), ov[3]));
      ov[4] = fmaf(mk, BF_LO(wl.z), fmaf(xk, BF_LO(wr.z), ov[4]));
      ov[5] = fmaf(mk, BF_HI(wl.z), fmaf(xk, BF_HI(wr.z), ov[5]));
      ov[6] = fmaf(mk, BF_LO(wl.w), fmaf(xk, BF_LO(wr.w), ov[6]));
      ov[7] = fmaf(mk, BF_HI(wl.w), fmaf(xk, BF_HI(wr.w), ov[7]));
    }
    // reduce over k-ranges (lane bits 3,4,5), then bias
#pragma unroll
    for (int jj = 0; jj < 8; ++jj) {
      ov[jj] += __shfl_xor(ov[jj], 8);
      ov[jj] += __shfl_xor(ov[jj], 16);
      ov[jj] += __shfl_xor(ov[jj], 32);
      ov[jj] += blv[jj];
    }

    if (mode == 0) {
      // relu + store bf16 h1 (one lane per j8)
#pragma unroll
      for (int jj = 0; jj < 8; ++jj) ov[jj] = fmaxf(ov[jj], 0.f);
      if (o == 0) {
        uint4 p;
        p.x = f2bf(ov[0]) | (f2bf(ov[1]) << 16);
        p.y = f2bf(ov[2]) | (f2bf(ov[3]) << 16);
        p.z = f2bf(ov[4]) | (f2bf(ov[5]) << 16);
        p.w = f2bf(ov[6]) | (f2bf(ov[7]) << 16);
        *(uint4*)(outB + (size_t)n * 64 + j8 * 8) = p;
      }
    } else {
      // fused classifier
      const float4* wc4 = (const float4*)Wc;
      float4 c00 = wc4[2 * j8], c01 = wc4[2 * j8 + 1];
      float4 c10 = wc4[16 + 2 * j8], c11 = wc4[16 + 2 * j8 + 1];
      float p0 = ov[0] * c00.x + ov[1] * c00.y + ov[2] * c00.z + ov[3] * c00.w +
                 ov[4] * c01.x + ov[5] * c01.y + ov[6] * c01.z + ov[7] * c01.w;
      float p1 = ov[0] * c10.x + ov[1] * c10.y + ov[2] * c10.z + ov[3] * c10.w +
                 ov[4] * c11.x + ov[5] * c11.y + ov[6] * c11.z + ov[7] * c11.w;
      p0 += __shfl_xor(p0, 1); p0 += __shfl_xor(p0, 2); p0 += __shfl_xor(p0, 4);
      p1 += __shfl_xor(p1, 1); p1 += __shfl_xor(p1, 2); p1 += __shfl_xor(p1, 4);
      if (lane == 0) {
        outF[(size_t)n * 2 + 0] = p0 + bc[0];
        outF[(size_t)n * 2 + 1] = p1 + bc[1];
      }
    }
  }
}

extern "C" void kernel_launch(void* const* d_in, const int* in_sizes, int n_in,
                              void* d_out, int out_size, void* d_ws,
                              size_t ws_size, hipStream_t stream) {
  const float* x   = (const float*)d_in[0];
  const int*   ei  = (const int*)d_in[1];
  const float* Wl1 = (const float*)d_in[2];
  const float* bl1 = (const float*)d_in[3];
  const float* Wr1 = (const float*)d_in[4];
  const float* Wl2 = (const float*)d_in[5];
  const float* bl2 = (const float*)d_in[6];
  const float* Wr2 = (const float*)d_in[7];
  const float* Wc  = (const float*)d_in[8];
  const float* bc  = (const float*)d_in[9];
  float* out = (float*)d_out;

  int nE = in_sizes[1] / 2;
  const int* src = ei;
  const int* dst = ei + nE;

  // Workspace: xb [N*64 bf16] | h1b [N*64 bf16] | degI [N] | rowstart [N] |
  //            cursor [N] | bsum [512] | adj [E]   (~31.6 MB)
  unsigned short* xb  = (unsigned short*)d_ws;
  unsigned short* h1b = xb + (size_t)N_NODES * D;
  int* degI = (int*)(h1b + (size_t)N_NODES * D);
  int* rowstart = degI + N_NODES;
  int* cursor = rowstart + N_NODES;
  int* bsum = cursor + N_NODES;
  int* adj = bsum + 512;

  hipMemsetAsync(degI, 0, N_NODES * sizeof(int), stream);

  dim3 blk(256);
  to_bf16_kernel<<<1024, blk, 0, stream>>>((const float4*)x, (uint4*)xb,
                                           N_NODES * D / 8);
  hist_kernel<<<2048, blk, 0, stream>>>(dst, degI, nE);
  scan_p1<<<NBLK_SCAN, blk, 0, stream>>>(degI, bsum);
  scan_p2<<<1, 512, 0, stream>>>(bsum, NBLK_SCAN);
  scan_p3<<<NBLK_SCAN, blk, 0, stream>>>(degI, bsum, rowstart, cursor);
  build_adj_kernel<<<2048, blk, 0, stream>>>(src, dst, cursor, adj, nE);

  // Layer 1: gather xb, self x(f32) -> h1b (bf16, relu)
  sage_fused_v4<<<1536, blk, 0, stream>>>(rowstart, degI, adj, x, xb, xb, Wl1,
                                          bl1, Wr1, Wc, bc, out, h1b, nE, 0);
  // Layer 2: gather h1b, self h1b -> out (f32, fused classifier)
  sage_fused_v4<<<1536, blk, 0, stream>>>(rowstart, degI, adj, x, h1b, h1b,
                                          Wl2, bl2, Wr2, Wc, bc, out, h1b, nE,
                                          1);
}

// Round 6
// 411.800 us; speedup vs baseline: 4.0317x; 4.0317x over previous
//
#include <hip/hip_runtime.h>

#define N_NODES 100000
#define D 64
#define ROWP 17  // float4 per padded WT row (272B rows, 16B aligned)
#define SCAN_CHUNK 256
#define NBLK_SCAN ((N_NODES + SCAN_CHUNK - 1) / SCAN_CHUNK)  // 391

__device__ __forceinline__ unsigned f2bf(float f) {  // RNE float->bf16 bits
  unsigned u = __float_as_uint(f);
  return (u + 0x7fffu + ((u >> 16) & 1u)) >> 16;
}
#define BF_LO(u) __uint_as_float(((unsigned)(u)) << 16)
#define BF_HI(u) __uint_as_float(((unsigned)(u)) & 0xffff0000u)

// ---------- bf16-ize feature table (8 floats / thread) ----------
__global__ void to_bf16_kernel(const float4* __restrict__ in,
                               uint4* __restrict__ outp, int n8) {
  int i = blockIdx.x * blockDim.x + threadIdx.x;
  int stride = gridDim.x * blockDim.x;
  for (; i < n8; i += stride) {
    float4 a = in[2 * i], b = in[2 * i + 1];
    uint4 r;
    r.x = f2bf(a.x) | (f2bf(a.y) << 16);
    r.y = f2bf(a.z) | (f2bf(a.w) << 16);
    r.z = f2bf(b.x) | (f2bf(b.y) << 16);
    r.w = f2bf(b.z) | (f2bf(b.w) << 16);
    outp[i] = r;
  }
}

// ---------- CSR build ----------
__global__ void hist_kernel(const int* __restrict__ dst, int* __restrict__ degI,
                            int nE) {
  int i = blockIdx.x * blockDim.x + threadIdx.x;
  int stride = gridDim.x * blockDim.x;
  for (int e = i; e < nE; e += stride) atomicAdd(&degI[dst[e]], 1);
}

__global__ void scan_p1(const int* __restrict__ degI, int* __restrict__ bsum) {
  int t = threadIdx.x, b = blockIdx.x;
  int i = b * SCAN_CHUNK + t;
  int v = (i < N_NODES) ? degI[i] : 0;
  for (int off = 32; off; off >>= 1) v += __shfl_down(v, off);
  __shared__ int ws4[4];
  if ((t & 63) == 0) ws4[t >> 6] = v;
  __syncthreads();
  if (t == 0) bsum[b] = ws4[0] + ws4[1] + ws4[2] + ws4[3];
}

__global__ void scan_p2(int* __restrict__ bsum, int nB) {
  __shared__ int s[512];
  int t = threadIdx.x;
  int orig = (t < nB) ? bsum[t] : 0;
  s[t] = orig;
  __syncthreads();
  for (int off = 1; off < 512; off <<= 1) {
    int v = (t >= off) ? s[t - off] : 0;
    __syncthreads();
    s[t] += v;
    __syncthreads();
  }
  if (t < nB) bsum[t] = s[t] - orig;
}

__global__ void scan_p3(const int* __restrict__ degI, const int* __restrict__ bsum,
                        int* __restrict__ rowstart, int* __restrict__ cursor) {
  __shared__ int s[SCAN_CHUNK];
  int t = threadIdx.x, b = blockIdx.x;
  int i = b * SCAN_CHUNK + t;
  int d = (i < N_NODES) ? degI[i] : 0;
  s[t] = d;
  __syncthreads();
  for (int off = 1; off < SCAN_CHUNK; off <<= 1) {
    int v = (t >= off) ? s[t - off] : 0;
    __syncthreads();
    s[t] += v;
    __syncthreads();
  }
  if (i < N_NODES) {
    int ex = s[t] - d + bsum[b];
    rowstart[i] = ex;
    cursor[i] = ex;
  }
}

__global__ void build_adj_kernel(const int* __restrict__ src,
                                 const int* __restrict__ dst,
                                 int* __restrict__ cursor, int* __restrict__ adj,
                                 int nE) {
  int i = blockIdx.x * blockDim.x + threadIdx.x;
  int stride = gridDim.x * blockDim.x;
  for (int e = i; e < nE; e += stride) {
    int d = dst[e];
    int p = atomicAdd(&cursor[d], 1);
    adj[p] = src[e];
  }
}

// ---------- Fused SAGE layer v5: v2 structure, bf16 gather table ----------
// Wave-per-node. Quarter-wave per edge (q = lane>>4), j4 = lane&15 owns
// features 4*j4..+3 (8B bf16 chunk). Gather: 4 edges per wave-load, 4
// independent loads (16 edges) per inner iteration. GEMV identical to v2:
// f32 weights in LDS, row-slot permute, in-register shfl broadcasts.

__global__ __launch_bounds__(512) void sage_fused_v5(
    const int* __restrict__ rowstart, const int* __restrict__ degI,
    const int* __restrict__ adj,
    const float* __restrict__ selfF,           // f32 self feats (mode 0)
    const unsigned short* __restrict__ selfB,  // bf16 self feats (mode 1)
    const unsigned short* __restrict__ gatB,   // bf16 gather table
    const float* __restrict__ Wl, const float* __restrict__ bl,
    const float* __restrict__ Wr, const float* __restrict__ Wc,
    const float* __restrict__ bc,
    float* __restrict__ outF, unsigned short* __restrict__ outB,
    int nE, int mode) {
  __shared__ float4 WlT4[64 * ROWP];
  __shared__ float4 WrT4[64 * ROWP];
  int tid = threadIdx.x;
  for (int i = tid; i < 1024; i += 512) {
    int k = i >> 4, j4s = i & 15;
    int slot = (k >> 4) + (k & 15) * 4;
    float4 wa, wb;
    wa.x = Wl[(4 * j4s + 0) * D + k];
    wa.y = Wl[(4 * j4s + 1) * D + k];
    wa.z = Wl[(4 * j4s + 2) * D + k];
    wa.w = Wl[(4 * j4s + 3) * D + k];
    wb.x = Wr[(4 * j4s + 0) * D + k];
    wb.y = Wr[(4 * j4s + 1) * D + k];
    wb.z = Wr[(4 * j4s + 2) * D + k];
    wb.w = Wr[(4 * j4s + 3) * D + k];
    WlT4[slot * ROWP + j4s] = wa;
    WrT4[slot * ROWP + j4s] = wb;
  }
  __syncthreads();

  int lane = tid & 63;
  int q = lane >> 4, j4 = lane & 15;
  float4 blr = ((const float4*)bl)[j4];
  float4 wc0 = ((const float4*)Wc)[j4];
  float4 wc1 = ((const float4*)Wc)[16 + j4];
  float bc0 = bc[0], bc1 = bc[1];

  int nWaves = (gridDim.x * blockDim.x) >> 6;
  int gw = (blockIdx.x * blockDim.x + tid) >> 6;

  for (int n = gw; n < N_NODES; n += nWaves) {
    int rs = rowstart[n];
    int dg = degI[n];
    // self features (f32 table mode 0, bf16 table mode 1)
    float4 xv;
    if (mode == 0) {
      xv = ((const float4*)selfF)[(size_t)n * 16 + j4];
    } else {
      uint2 v = ((const uint2*)(selfB + (size_t)n * 64))[j4];
      xv.x = BF_LO(v.x); xv.y = BF_HI(v.x);
      xv.z = BF_LO(v.y); xv.w = BF_HI(v.y);
    }
    float4 acc = make_float4(0.f, 0.f, 0.f, 0.f);
    const uint2* gt = (const uint2*)gatB;  // 16 uint2 per row
    for (int base = 0; base < dg; base += 64) {
      int cnt = min(dg - base, 64);
      int aidx = rs + base + lane;
      int a = adj[min(aidx, nE - 1)];
      int nIter = (cnt + 3) >> 2;
      for (int t0 = 0; t0 < nIter; t0 += 4) {
        uint2 v0, v1, v2, v3;
        float m0, m1, m2, m3;
        int el, nb;
        bool ok;
        el = (t0 + 0) * 4 + q; ok = el < cnt;
        nb = __shfl(a, el < 64 ? el : 0); nb = ok ? nb : n;
        v0 = gt[(size_t)nb * 16 + j4]; m0 = ok ? 1.f : 0.f;
        el = (t0 + 1) * 4 + q; ok = el < cnt;
        nb = __shfl(a, el < 64 ? el : 0); nb = ok ? nb : n;
        v1 = gt[(size_t)nb * 16 + j4]; m1 = ok ? 1.f : 0.f;
        el = (t0 + 2) * 4 + q; ok = el < cnt;
        nb = __shfl(a, el < 64 ? el : 0); nb = ok ? nb : n;
        v2 = gt[(size_t)nb * 16 + j4]; m2 = ok ? 1.f : 0.f;
        el = (t0 + 3) * 4 + q; ok = el < cnt;
        nb = __shfl(a, el < 64 ? el : 0); nb = ok ? nb : n;
        v3 = gt[(size_t)nb * 16 + j4]; m3 = ok ? 1.f : 0.f;
        acc.x = fmaf(BF_LO(v0.x), m0, acc.x);
        acc.y = fmaf(BF_HI(v0.x), m0, acc.y);
        acc.z = fmaf(BF_LO(v0.y), m0, acc.z);
        acc.w = fmaf(BF_HI(v0.y), m0, acc.w);
        acc.x = fmaf(BF_LO(v1.x), m1, acc.x);
        acc.y = fmaf(BF_HI(v1.x), m1, acc.y);
        acc.z = fmaf(BF_LO(v1.y), m1, acc.z);
        acc.w = fmaf(BF_HI(v1.y), m1, acc.w);
        acc.x = fmaf(BF_LO(v2.x), m2, acc.x);
        acc.y = fmaf(BF_HI(v2.x), m2, acc.y);
        acc.z = fmaf(BF_LO(v2.y), m2, acc.z);
        acc.w = fmaf(BF_HI(v2.y), m2, acc.w);
        acc.x = fmaf(BF_LO(v3.x), m3, acc.x);
        acc.y = fmaf(BF_HI(v3.x), m3, acc.y);
        acc.z = fmaf(BF_LO(v3.y), m3, acc.z);
        acc.w = fmaf(BF_HI(v3.y), m3, acc.w);
      }
    }
    // cross-quarter reduce: every lane ends with full sums for its 4 features
    acc.x += __shfl_xor(acc.x, 16); acc.x += __shfl_xor(acc.x, 32);
    acc.y += __shfl_xor(acc.y, 16); acc.y += __shfl_xor(acc.y, 32);
    acc.z += __shfl_xor(acc.z, 16); acc.z += __shfl_xor(acc.z, 32);
    acc.w += __shfl_xor(acc.w, 16); acc.w += __shfl_xor(acc.w, 32);
    float inv = 1.f / (float)max(dg, 1);
    float4 mean = make_float4(acc.x * inv, acc.y * inv, acc.z * inv, acc.w * inv);

    // dual GEMV: k = q*16 + kg*4 + kc
    float4 o = make_float4(0.f, 0.f, 0.f, 0.f);
#pragma unroll
    for (int kg = 0; kg < 4; ++kg) {
#pragma unroll
      for (int kc = 0; kc < 4; ++kc) {
        int slot = q + 16 * kg + 4 * kc;  // = (k>>4) + 4*(k&15)
        float4 wl4 = WlT4[slot * ROWP + j4];
        float4 wr4 = WrT4[slot * ROWP + j4];
        int srcl = q * 4 + kg;  // lane holding m[k]/x[k]
        float mc = (kc == 0) ? mean.x : (kc == 1) ? mean.y : (kc == 2) ? mean.z : mean.w;
        float xc = (kc == 0) ? xv.x : (kc == 1) ? xv.y : (kc == 2) ? xv.z : xv.w;
        float mkv = __shfl(mc, srcl);
        float xkv = __shfl(xc, srcl);
        o.x = fmaf(mkv, wl4.x, fmaf(xkv, wr4.x, o.x));
        o.y = fmaf(mkv, wl4.y, fmaf(xkv, wr4.y, o.y));
        o.z = fmaf(mkv, wl4.z, fmaf(xkv, wr4.z, o.z));
        o.w = fmaf(mkv, wl4.w, fmaf(xkv, wr4.w, o.w));
      }
    }
    // reduce partial k-ranges across quarters
    o.x += __shfl_xor(o.x, 16); o.x += __shfl_xor(o.x, 32);
    o.y += __shfl_xor(o.y, 16); o.y += __shfl_xor(o.y, 32);
    o.z += __shfl_xor(o.z, 16); o.z += __shfl_xor(o.z, 32);
    o.w += __shfl_xor(o.w, 16); o.w += __shfl_xor(o.w, 32);
    o.x += blr.x; o.y += blr.y; o.z += blr.z; o.w += blr.w;

    if (mode == 0) {
      // relu + store bf16 h1 (quarter 0 lanes: 16 x 8B = 128B contiguous)
      o.x = fmaxf(o.x, 0.f); o.y = fmaxf(o.y, 0.f);
      o.z = fmaxf(o.z, 0.f); o.w = fmaxf(o.w, 0.f);
      if (lane < 16) {
        uint2 p;
        p.x = f2bf(o.x) | (f2bf(o.y) << 16);
        p.y = f2bf(o.z) | (f2bf(o.w) << 16);
        ((uint2*)(outB + (size_t)n * 64))[j4] = p;
      }
    } else {
      float4 wc = (q & 1) ? wc1 : wc0;
      float p = o.x * wc.x + o.y * wc.y + o.z * wc.z + o.w * wc.w;
      p += __shfl_xor(p, 1); p += __shfl_xor(p, 2);
      p += __shfl_xor(p, 4); p += __shfl_xor(p, 8);
      if (lane == 0) outF[(size_t)n * 2 + 0] = p + bc0;
      if (lane == 16) outF[(size_t)n * 2 + 1] = p + bc1;
    }
  }
}

extern "C" void kernel_launch(void* const* d_in, const int* in_sizes, int n_in,
                              void* d_out, int out_size, void* d_ws,
                              size_t ws_size, hipStream_t stream) {
  const float* x   = (const float*)d_in[0];
  const int*   ei  = (const int*)d_in[1];
  const float* Wl1 = (const float*)d_in[2];
  const float* bl1 = (const float*)d_in[3];
  const float* Wr1 = (const float*)d_in[4];
  const float* Wl2 = (const float*)d_in[5];
  const float* bl2 = (const float*)d_in[6];
  const float* Wr2 = (const float*)d_in[7];
  const float* Wc  = (const float*)d_in[8];
  const float* bc  = (const float*)d_in[9];
  float* out = (float*)d_out;

  int nE = in_sizes[1] / 2;
  const int* src = ei;
  const int* dst = ei + nE;

  // Workspace: xb [N*64 bf16] | h1b [N*64 bf16] | degI [N] | rowstart [N] |
  //            cursor [N] | bsum [512] | adj [E]   (~31.6 MB)
  unsigned short* xb  = (unsigned short*)d_ws;
  unsigned short* h1b = xb + (size_t)N_NODES * D;
  int* degI = (int*)(h1b + (size_t)N_NODES * D);
  int* rowstart = degI + N_NODES;
  int* cursor = rowstart + N_NODES;
  int* bsum = cursor + N_NODES;
  int* adj = bsum + 512;

  hipMemsetAsync(degI, 0, N_NODES * sizeof(int), stream);

  dim3 blk(256);
  to_bf16_kernel<<<1024, blk, 0, stream>>>((const float4*)x, (uint4*)xb,
                                           N_NODES * D / 8);
  hist_kernel<<<2048, blk, 0, stream>>>(dst, degI, nE);
  scan_p1<<<NBLK_SCAN, blk, 0, stream>>>(degI, bsum);
  scan_p2<<<1, 512, 0, stream>>>(bsum, NBLK_SCAN);
  scan_p3<<<NBLK_SCAN, blk, 0, stream>>>(degI, bsum, rowstart, cursor);
  build_adj_kernel<<<2048, blk, 0, stream>>>(src, dst, cursor, adj, nE);

  // Layer 1: gather xb, self x(f32) -> h1b (bf16, relu)
  sage_fused_v5<<<1024, 512, 0, stream>>>(rowstart, degI, adj, x, xb, xb, Wl1,
                                          bl1, Wr1, Wc, bc, out, h1b, nE, 0);
  // Layer 2: gather h1b, self h1b -> out (f32, fused classifier)
  sage_fused_v5<<<1024, 512, 0, stream>>>(rowstart, degI, adj, x, h1b, h1b,
                                          Wl2, bl2, Wr2, Wc, bc, out, h1b, nE,
                                          1);
}

// Round 7
// 311.836 us; speedup vs baseline: 5.3241x; 1.3206x over previous
//
#include <hip/hip_runtime.h>

#define N_NODES 100000
#define D 64
#define ROWP 17  // float4 per padded WT row
#define SCAN_CHUNK 256
#define NBLK_SCAN ((N_NODES + SCAN_CHUNK - 1) / SCAN_CHUNK)  // 391

__device__ __forceinline__ unsigned f2bf(float f) {  // RNE float->bf16 bits
  unsigned u = __float_as_uint(f);
  return (u + 0x7fffu + ((u >> 16) & 1u)) >> 16;
}
#define BF_LO(u) __uint_as_float(((unsigned)(u)) << 16)
#define BF_HI(u) __uint_as_float(((unsigned)(u)) & 0xffff0000u)

// ---------- CSR build ----------
__global__ void hist_kernel(const int* __restrict__ dst, int* __restrict__ degI,
                            int nE) {
  int i = blockIdx.x * blockDim.x + threadIdx.x;
  int stride = gridDim.x * blockDim.x;
  for (int e = i; e < nE; e += stride) atomicAdd(&degI[dst[e]], 1);
}

__global__ void scan_p1(const int* __restrict__ degI, int* __restrict__ bsum) {
  int t = threadIdx.x, b = blockIdx.x;
  int i = b * SCAN_CHUNK + t;
  int v = (i < N_NODES) ? degI[i] : 0;
  for (int off = 32; off; off >>= 1) v += __shfl_down(v, off);
  __shared__ int ws4[4];
  if ((t & 63) == 0) ws4[t >> 6] = v;
  __syncthreads();
  if (t == 0) bsum[b] = ws4[0] + ws4[1] + ws4[2] + ws4[3];
}

__global__ void scan_p2(int* __restrict__ bsum, int nB) {
  __shared__ int s[512];
  int t = threadIdx.x;
  int orig = (t < nB) ? bsum[t] : 0;
  s[t] = orig;
  __syncthreads();
  for (int off = 1; off < 512; off <<= 1) {
    int v = (t >= off) ? s[t - off] : 0;
    __syncthreads();
    s[t] += v;
    __syncthreads();
  }
  if (t < nB) bsum[t] = s[t] - orig;
}

__global__ void scan_p3(const int* __restrict__ degI, const int* __restrict__ bsum,
                        int* __restrict__ rowstart, int* __restrict__ cursor) {
  __shared__ int s[SCAN_CHUNK];
  int t = threadIdx.x, b = blockIdx.x;
  int i = b * SCAN_CHUNK + t;
  int d = (i < N_NODES) ? degI[i] : 0;
  s[t] = d;
  __syncthreads();
  for (int off = 1; off < SCAN_CHUNK; off <<= 1) {
    int v = (t >= off) ? s[t - off] : 0;
    __syncthreads();
    s[t] += v;
    __syncthreads();
  }
  if (i < N_NODES) {
    int ex = s[t] - d + bsum[b];
    rowstart[i] = ex;
    cursor[i] = ex;
  }
}

__global__ void build_adj_kernel(const int* __restrict__ src,
                                 const int* __restrict__ dst,
                                 int* __restrict__ cursor, int* __restrict__ adj,
                                 int nE) {
  int i = blockIdx.x * blockDim.x + threadIdx.x;
  int stride = gridDim.x * blockDim.x;
  for (int e = i; e < nE; e += stride) {
    int d = dst[e];
    int p = atomicAdd(&cursor[d], 1);
    adj[p] = src[e];
  }
}

// ---------- Fold classifier through layer 2 ----------
// A2 = Wc@Wl2 [2x64], B2 = Wc@Wr2 [2x64], bf = Wc@b_l2 + bc [2]
__global__ void wfold_kernel(const float* __restrict__ Wc,
                             const float* __restrict__ Wl2,
                             const float* __restrict__ Wr2,
                             const float* __restrict__ bl2,
                             const float* __restrict__ bc,
                             float* __restrict__ A2, float* __restrict__ B2,
                             float* __restrict__ bfv) {
  int t = threadIdx.x;  // 128 threads
  int c = t >> 6, k = t & 63;
  float sa = 0.f, sb = 0.f;
  for (int j = 0; j < 64; ++j) {
    float w = Wc[c * 64 + j];
    sa = fmaf(w, Wl2[j * 64 + k], sa);
    sb = fmaf(w, Wr2[j * 64 + k], sb);
  }
  A2[c * 64 + k] = sa;
  B2[c * 64 + k] = sb;
  if (t < 2) {
    float s = bc[t];
    for (int j = 0; j < 64; ++j) s = fmaf(Wc[t * 64 + j], bl2[j], s);
    bfv[t] = s;
  }
}

// ---------- transform1: t1 = x@Wl1^T (bf16), r1 = x@Wr1^T + b_l1 (f32) ----
// Wave-per-node dual GEMV (v2/v5-proven structure): f32 W in LDS with
// row-slot permute; x broadcast via in-register shfl.
__global__ __launch_bounds__(512) void transform1_kernel(
    const float* __restrict__ x, const float* __restrict__ Wl,
    const float* __restrict__ bl, const float* __restrict__ Wr,
    unsigned short* __restrict__ t1, float* __restrict__ r1) {
  __shared__ float4 WlT4[64 * ROWP];
  __shared__ float4 WrT4[64 * ROWP];
  int tid = threadIdx.x;
  for (int i = tid; i < 1024; i += 512) {
    int k = i >> 4, j4s = i & 15;
    int slot = (k >> 4) + (k & 15) * 4;
    float4 wa, wb;
    wa.x = Wl[(4 * j4s + 0) * D + k];
    wa.y = Wl[(4 * j4s + 1) * D + k];
    wa.z = Wl[(4 * j4s + 2) * D + k];
    wa.w = Wl[(4 * j4s + 3) * D + k];
    wb.x = Wr[(4 * j4s + 0) * D + k];
    wb.y = Wr[(4 * j4s + 1) * D + k];
    wb.z = Wr[(4 * j4s + 2) * D + k];
    wb.w = Wr[(4 * j4s + 3) * D + k];
    WlT4[slot * ROWP + j4s] = wa;
    WrT4[slot * ROWP + j4s] = wb;
  }
  __syncthreads();

  int lane = tid & 63;
  int q = lane >> 4, j4 = lane & 15;
  float4 blr = ((const float4*)bl)[j4];

  int nWaves = (gridDim.x * 512) >> 6;
  int gw = (blockIdx.x * 512 + tid) >> 6;

  for (int n = gw; n < N_NODES; n += nWaves) {
    float4 xv = ((const float4*)x)[(size_t)n * 16 + j4];
    float4 o1 = make_float4(0.f, 0.f, 0.f, 0.f);
    float4 o2 = make_float4(0.f, 0.f, 0.f, 0.f);
#pragma unroll
    for (int kg = 0; kg < 4; ++kg) {
#pragma unroll
      for (int kc = 0; kc < 4; ++kc) {
        int slot = q + 16 * kg + 4 * kc;
        float4 wl4 = WlT4[slot * ROWP + j4];
        float4 wr4 = WrT4[slot * ROWP + j4];
        float xc = (kc == 0) ? xv.x : (kc == 1) ? xv.y : (kc == 2) ? xv.z : xv.w;
        float xkv = __shfl(xc, q * 4 + kg);
        o1.x = fmaf(xkv, wl4.x, o1.x); o1.y = fmaf(xkv, wl4.y, o1.y);
        o1.z = fmaf(xkv, wl4.z, o1.z); o1.w = fmaf(xkv, wl4.w, o1.w);
        o2.x = fmaf(xkv, wr4.x, o2.x); o2.y = fmaf(xkv, wr4.y, o2.y);
        o2.z = fmaf(xkv, wr4.z, o2.z); o2.w = fmaf(xkv, wr4.w, o2.w);
      }
    }
    o1.x += __shfl_xor(o1.x, 16); o1.x += __shfl_xor(o1.x, 32);
    o1.y += __shfl_xor(o1.y, 16); o1.y += __shfl_xor(o1.y, 32);
    o1.z += __shfl_xor(o1.z, 16); o1.z += __shfl_xor(o1.z, 32);
    o1.w += __shfl_xor(o1.w, 16); o1.w += __shfl_xor(o1.w, 32);
    o2.x += __shfl_xor(o2.x, 16); o2.x += __shfl_xor(o2.x, 32);
    o2.y += __shfl_xor(o2.y, 16); o2.y += __shfl_xor(o2.y, 32);
    o2.z += __shfl_xor(o2.z, 16); o2.z += __shfl_xor(o2.z, 32);
    o2.w += __shfl_xor(o2.w, 16); o2.w += __shfl_xor(o2.w, 32);
    o2.x += blr.x; o2.y += blr.y; o2.z += blr.z; o2.w += blr.w;
    if (lane < 16) {
      uint2 p;
      p.x = f2bf(o1.x) | (f2bf(o1.y) << 16);
      p.y = f2bf(o1.z) | (f2bf(o1.w) << 16);
      ((uint2*)(t1 + (size_t)n * 64))[j4] = p;
      ((float4*)r1)[(size_t)n * 16 + j4] = o2;
    }
  }
}

// ---------- gather1: pure CSR mean of t1, + r1, relu, project to 2+2 ----
// Wave-per-node. lane = o*8+j8: j8 owns 16B chunk (8 bf16) of the row; 8
// edge-slots per load instruction; 2 independent loads (16 edges) in flight.
#define ACC8(v, m)                       \
  acc[0] = fmaf(BF_LO(v.x), m, acc[0]);  \
  acc[1] = fmaf(BF_HI(v.x), m, acc[1]);  \
  acc[2] = fmaf(BF_LO(v.y), m, acc[2]);  \
  acc[3] = fmaf(BF_HI(v.y), m, acc[3]);  \
  acc[4] = fmaf(BF_LO(v.z), m, acc[4]);  \
  acc[5] = fmaf(BF_HI(v.z), m, acc[5]);  \
  acc[6] = fmaf(BF_LO(v.w), m, acc[6]);  \
  acc[7] = fmaf(BF_HI(v.w), m, acc[7]);

__global__ __launch_bounds__(512) void gather1_kernel(
    const int* __restrict__ rowstart, const int* __restrict__ degI,
    const int* __restrict__ adj, const unsigned short* __restrict__ t1,
    const float* __restrict__ r1, const float* __restrict__ A2,
    const float* __restrict__ B2, float2* __restrict__ g2,
    float2* __restrict__ s2, int nE) {
  int tid = threadIdx.x, lane = tid & 63;
  int o = lane >> 3, j8 = lane & 7;
  // preload projection rows (chunk j8 of each of the 4 projection vectors)
  float pa0[8], pa1[8], pb0[8], pb1[8];
  {
    float4 a = ((const float4*)A2)[j8 * 2], b = ((const float4*)A2)[j8 * 2 + 1];
    pa0[0] = a.x; pa0[1] = a.y; pa0[2] = a.z; pa0[3] = a.w;
    pa0[4] = b.x; pa0[5] = b.y; pa0[6] = b.z; pa0[7] = b.w;
    a = ((const float4*)A2)[16 + j8 * 2]; b = ((const float4*)A2)[16 + j8 * 2 + 1];
    pa1[0] = a.x; pa1[1] = a.y; pa1[2] = a.z; pa1[3] = a.w;
    pa1[4] = b.x; pa1[5] = b.y; pa1[6] = b.z; pa1[7] = b.w;
    a = ((const float4*)B2)[j8 * 2]; b = ((const float4*)B2)[j8 * 2 + 1];
    pb0[0] = a.x; pb0[1] = a.y; pb0[2] = a.z; pb0[3] = a.w;
    pb0[4] = b.x; pb0[5] = b.y; pb0[6] = b.z; pb0[7] = b.w;
    a = ((const float4*)B2)[16 + j8 * 2]; b = ((const float4*)B2)[16 + j8 * 2 + 1];
    pb1[0] = a.x; pb1[1] = a.y; pb1[2] = a.z; pb1[3] = a.w;
    pb1[4] = b.x; pb1[5] = b.y; pb1[6] = b.z; pb1[7] = b.w;
  }

  int gw = (blockIdx.x * 512 + tid) >> 6;
  int nWaves = (gridDim.x * 512) >> 6;

  for (int n = gw; n < N_NODES; n += nWaves) {
    int rs = rowstart[n], dg = degI[n];
    float acc[8] = {0.f, 0.f, 0.f, 0.f, 0.f, 0.f, 0.f, 0.f};
    for (int base = 0; base < dg; base += 64) {
      int cnt = min(dg - base, 64);
      int a = adj[min(rs + base + lane, nE - 1)];
      for (int t = 0; t < cnt; t += 16) {
        int el0 = t + o, el1 = t + 8 + o;  // <= 63
        int nb0 = __shfl(a, el0);
        int nb1 = __shfl(a, el1);
        bool ok0 = el0 < cnt, ok1 = el1 < cnt;
        nb0 = ok0 ? nb0 : n;
        nb1 = ok1 ? nb1 : n;
        uint4 v0 = *(const uint4*)(t1 + (size_t)nb0 * 64 + j8 * 8);
        uint4 v1 = *(const uint4*)(t1 + (size_t)nb1 * 64 + j8 * 8);
        float m0 = ok0 ? 1.f : 0.f, m1 = ok1 ? 1.f : 0.f;
        ACC8(v0, m0)
        ACC8(v1, m1)
      }
    }
    // reduce partial sums across the 8 edge-slots (lane bits 3,4,5)
#pragma unroll
    for (int jj = 0; jj < 8; ++jj) {
      acc[jj] += __shfl_xor(acc[jj], 8);
      acc[jj] += __shfl_xor(acc[jj], 16);
      acc[jj] += __shfl_xor(acc[jj], 32);
    }
    float inv = 1.f / (float)max(dg, 1);
    float4 ra = ((const float4*)r1)[(size_t)n * 16 + j8 * 2];
    float4 rb = ((const float4*)r1)[(size_t)n * 16 + j8 * 2 + 1];
    float h[8];
    h[0] = fmaxf(fmaf(acc[0], inv, ra.x), 0.f);
    h[1] = fmaxf(fmaf(acc[1], inv, ra.y), 0.f);
    h[2] = fmaxf(fmaf(acc[2], inv, ra.z), 0.f);
    h[3] = fmaxf(fmaf(acc[3], inv, ra.w), 0.f);
    h[4] = fmaxf(fmaf(acc[4], inv, rb.x), 0.f);
    h[5] = fmaxf(fmaf(acc[5], inv, rb.y), 0.f);
    h[6] = fmaxf(fmaf(acc[6], inv, rb.z), 0.f);
    h[7] = fmaxf(fmaf(acc[7], inv, rb.w), 0.f);
    // 4 dot products: per-lane partial over 8 feats, reduce over j8 (bits 0-2)
    float d0 = 0.f, d1 = 0.f, d2 = 0.f, d3 = 0.f;
#pragma unroll
    for (int i = 0; i < 8; ++i) {
      d0 = fmaf(h[i], pa0[i], d0);
      d1 = fmaf(h[i], pa1[i], d1);
      d2 = fmaf(h[i], pb0[i], d2);
      d3 = fmaf(h[i], pb1[i], d3);
    }
    d0 += __shfl_xor(d0, 1); d0 += __shfl_xor(d0, 2); d0 += __shfl_xor(d0, 4);
    d1 += __shfl_xor(d1, 1); d1 += __shfl_xor(d1, 2); d1 += __shfl_xor(d1, 4);
    d2 += __shfl_xor(d2, 1); d2 += __shfl_xor(d2, 2); d2 += __shfl_xor(d2, 4);
    d3 += __shfl_xor(d3, 1); d3 += __shfl_xor(d3, 2); d3 += __shfl_xor(d3, 4);
    if (lane == 0) {
      g2[n] = make_float2(d0, d1);
      s2[n] = make_float2(d2, d3);
    }
  }
}

// ---------- gather2: out[n] = mean_j(g2[j]) + s2[n] + bf ----------
// Quarter-wave per node (16 lanes each).
__global__ __launch_bounds__(256) void gather2_kernel(
    const int* __restrict__ rowstart, const int* __restrict__ degI,
    const int* __restrict__ adj, const float2* __restrict__ g2,
    const float2* __restrict__ s2, const float* __restrict__ bfv,
    float* __restrict__ out, int nE) {
  int tid = threadIdx.x, lane = tid & 63;
  int q = lane >> 4, l16 = lane & 15;
  float bf0 = bfv[0], bf1 = bfv[1];
  int gq = ((blockIdx.x * 256 + tid) >> 6) * 4 + q;
  int strideN = ((gridDim.x * 256) >> 6) * 4;
  for (int n = gq; n < N_NODES; n += strideN) {
    int rs = rowstart[n], dg = degI[n];
    float s0 = 0.f, s1 = 0.f;
    for (int base = 0; base < dg; base += 16) {
      int e = base + l16;
      int a = adj[min(rs + e, nE - 1)];
      float2 v = g2[a];
      float m = (e < dg) ? 1.f : 0.f;
      s0 = fmaf(v.x, m, s0);
      s1 = fmaf(v.y, m, s1);
    }
    s0 += __shfl_xor(s0, 1); s0 += __shfl_xor(s0, 2);
    s0 += __shfl_xor(s0, 4); s0 += __shfl_xor(s0, 8);
    s1 += __shfl_xor(s1, 1); s1 += __shfl_xor(s1, 2);
    s1 += __shfl_xor(s1, 4); s1 += __shfl_xor(s1, 8);
    if (l16 == 0) {
      float inv = 1.f / (float)max(dg, 1);
      float2 sv = s2[n];
      out[(size_t)n * 2 + 0] = fmaf(s0, inv, sv.x) + bf0;
      out[(size_t)n * 2 + 1] = fmaf(s1, inv, sv.y) + bf1;
    }
  }
}

extern "C" void kernel_launch(void* const* d_in, const int* in_sizes, int n_in,
                              void* d_out, int out_size, void* d_ws,
                              size_t ws_size, hipStream_t stream) {
  const float* x   = (const float*)d_in[0];
  const int*   ei  = (const int*)d_in[1];
  const float* Wl1 = (const float*)d_in[2];
  const float* bl1 = (const float*)d_in[3];
  const float* Wr1 = (const float*)d_in[4];
  const float* Wl2 = (const float*)d_in[5];
  const float* bl2 = (const float*)d_in[6];
  const float* Wr2 = (const float*)d_in[7];
  const float* Wc  = (const float*)d_in[8];
  const float* bc  = (const float*)d_in[9];
  float* out = (float*)d_out;

  int nE = in_sizes[1] / 2;
  const int* src = ei;
  const int* dst = ei + nE;

  // Workspace (~46.8 MB): r1 f32[N*64] | t1 bf16[N*64] | g2 f2[N] | s2 f2[N]
  //   | A2[128] B2[128] bf[4] | degI[N] rowstart[N] cursor[N] bsum[512] adj[E]
  float* r1 = (float*)d_ws;
  unsigned short* t1 = (unsigned short*)(r1 + (size_t)N_NODES * D);
  float2* g2 = (float2*)(t1 + (size_t)N_NODES * D);
  float2* s2 = g2 + N_NODES;
  float* A2 = (float*)(s2 + N_NODES);
  float* B2 = A2 + 128;
  float* bfv = B2 + 128;
  int* degI = (int*)(bfv + 4);
  int* rowstart = degI + N_NODES;
  int* cursor = rowstart + N_NODES;
  int* bsum = cursor + N_NODES;
  int* adj = bsum + 512;

  hipMemsetAsync(degI, 0, N_NODES * sizeof(int), stream);

  dim3 blk(256);
  hist_kernel<<<2048, blk, 0, stream>>>(dst, degI, nE);
  scan_p1<<<NBLK_SCAN, blk, 0, stream>>>(degI, bsum);
  scan_p2<<<1, 512, 0, stream>>>(bsum, NBLK_SCAN);
  scan_p3<<<NBLK_SCAN, blk, 0, stream>>>(degI, bsum, rowstart, cursor);
  build_adj_kernel<<<2048, blk, 0, stream>>>(src, dst, cursor, adj, nE);

  wfold_kernel<<<1, 128, 0, stream>>>(Wc, Wl2, Wr2, bl2, bc, A2, B2, bfv);
  transform1_kernel<<<1024, 512, 0, stream>>>(x, Wl1, bl1, Wr1, t1, r1);
  gather1_kernel<<<1024, 512, 0, stream>>>(rowstart, degI, adj, t1, r1, A2,
                                           B2, g2, s2, nE);
  gather2_kernel<<<512, blk, 0, stream>>>(rowstart, degI, adj, g2, s2, bfv,
                                          out, nE);
}

// Round 8
// 193.059 us; speedup vs baseline: 8.5997x; 1.6152x over previous
//
#include <hip/hip_runtime.h>

#define N_NODES 100000
#define D 64
#define ROWP 17  // float4 per padded WT row
#define NBUCK 391         // buckets of 256 nodes: dst>>8
#define NBLK_A 512        // blocks in count/place passes
#define GCNT_N (NBUCK * NBLK_A)            // 200192
#define NCHUNK ((GCNT_N + 255) / 256)      // 782 scan chunks

__device__ __forceinline__ unsigned f2bf(float f) {  // RNE float->bf16 bits
  unsigned u = __float_as_uint(f);
  return (u + 0x7fffu + ((u >> 16) & 1u)) >> 16;
}
#define BF_LO(u) __uint_as_float(((unsigned)(u)) << 16)
#define BF_HI(u) __uint_as_float(((unsigned)(u)) & 0xffff0000u)

// ---------- counting-sort CSR build (LDS atomics only) ----------

// Pass A: per-block bucket histogram.
__global__ __launch_bounds__(256) void passA_count(const int* __restrict__ dst,
                                                   int* __restrict__ gcnt,
                                                   int nE, int ec) {
  __shared__ int cnt[NBUCK];
  int t = threadIdx.x, blk = blockIdx.x;
  for (int i = t; i < NBUCK; i += 256) cnt[i] = 0;
  __syncthreads();
  int e0 = blk * ec, e1 = min(e0 + ec, nE);
  for (int e = e0 + t; e < e1; e += 256) atomicAdd(&cnt[dst[e] >> 8], 1);
  __syncthreads();
  for (int b = t; b < NBUCK; b += 256) gcnt[b * NBLK_A + blk] = cnt[b];
}

// Scan of gcnt (200192 ints): chunk sums -> scan sums -> write exclusive.
__global__ void gscan_p1(const int* __restrict__ g, int* __restrict__ csum) {
  int t = threadIdx.x, b = blockIdx.x;
  int i = b * 256 + t;
  int v = (i < GCNT_N) ? g[i] : 0;
  for (int off = 32; off; off >>= 1) v += __shfl_down(v, off);
  __shared__ int ws4[4];
  if ((t & 63) == 0) ws4[t >> 6] = v;
  __syncthreads();
  if (t == 0) csum[b] = ws4[0] + ws4[1] + ws4[2] + ws4[3];
}

__global__ void gscan_p2(int* __restrict__ csum, int nB) {
  __shared__ int s[1024];
  int t = threadIdx.x;
  int orig = (t < nB) ? csum[t] : 0;
  s[t] = orig;
  __syncthreads();
  for (int off = 1; off < 1024; off <<= 1) {
    int v = (t >= off) ? s[t - off] : 0;
    __syncthreads();
    s[t] += v;
    __syncthreads();
  }
  if (t < nB) csum[t] = s[t] - orig;  // exclusive block offsets
}

__global__ void gscan_p3(int* __restrict__ g, const int* __restrict__ csum) {
  __shared__ int s[256];
  int t = threadIdx.x, b = blockIdx.x;
  int i = b * 256 + t;
  int d = (i < GCNT_N) ? g[i] : 0;
  s[t] = d;
  __syncthreads();
  for (int off = 1; off < 256; off <<= 1) {
    int v = (t >= off) ? s[t - off] : 0;
    __syncthreads();
    s[t] += v;
    __syncthreads();
  }
  if (i < GCNT_N) g[i] = s[t] - d + csum[b];  // exclusive
}

// Pass C: scatter (dst,src) pairs into bucket-sorted order.
__global__ __launch_bounds__(256) void passC_place(const int* __restrict__ src,
                                                   const int* __restrict__ dst,
                                                   const int* __restrict__ S,
                                                   uint2* __restrict__ pairs,
                                                   int nE, int ec) {
  __shared__ int cur[NBUCK];
  int t = threadIdx.x, blk = blockIdx.x;
  for (int b = t; b < NBUCK; b += 256) cur[b] = S[b * NBLK_A + blk];
  __syncthreads();
  int e0 = blk * ec, e1 = min(e0 + ec, nE);
  for (int e = e0 + t; e < e1; e += 256) {
    int d = dst[e];
    int p = atomicAdd(&cur[d >> 8], 1);
    pairs[p] = make_uint2((unsigned)d, (unsigned)src[e]);
  }
}

// Pass D: one block per bucket -> per-node rowstart/deg/adj (local LDS CSR).
__global__ __launch_bounds__(256) void passD_csr(const uint2* __restrict__ pairs,
                                                 const int* __restrict__ S,
                                                 int* __restrict__ rowstart,
                                                 int* __restrict__ degI,
                                                 int* __restrict__ adj, int nE) {
  __shared__ int lh[256];
  __shared__ int sc[256];
  __shared__ int cur[256];
  int t = threadIdx.x, b = blockIdx.x;
  int base = S[b * NBLK_A];
  int end = (b == NBUCK - 1) ? nE : S[(b + 1) * NBLK_A];
  lh[t] = 0;
  __syncthreads();
  for (int p = base + t; p < end; p += 256) atomicAdd(&lh[pairs[p].x & 255], 1);
  __syncthreads();
  int d = lh[t];
  sc[t] = d;
  __syncthreads();
  for (int off = 1; off < 256; off <<= 1) {
    int v = (t >= off) ? sc[t - off] : 0;
    __syncthreads();
    sc[t] += v;
    __syncthreads();
  }
  int ex = sc[t] - d;  // exclusive local offset
  int node = b * 256 + t;
  if (node < N_NODES) {
    rowstart[node] = base + ex;
    degI[node] = d;
  }
  cur[t] = base + ex;
  __syncthreads();
  for (int p = base + t; p < end; p += 256) {
    uint2 e = pairs[p];
    int slot = atomicAdd(&cur[e.x & 255], 1);
    adj[slot] = (int)e.y;
  }
}

// ---------- Fold classifier through layer 2 ----------
__global__ void wfold_kernel(const float* __restrict__ Wc,
                             const float* __restrict__ Wl2,
                             const float* __restrict__ Wr2,
                             const float* __restrict__ bl2,
                             const float* __restrict__ bc,
                             float* __restrict__ A2, float* __restrict__ B2,
                             float* __restrict__ bfv) {
  int t = threadIdx.x;  // 128 threads
  int c = t >> 6, k = t & 63;
  float sa = 0.f, sb = 0.f;
  for (int j = 0; j < 64; ++j) {
    float w = Wc[c * 64 + j];
    sa = fmaf(w, Wl2[j * 64 + k], sa);
    sb = fmaf(w, Wr2[j * 64 + k], sb);
  }
  A2[c * 64 + k] = sa;
  B2[c * 64 + k] = sb;
  if (t < 2) {
    float s = bc[t];
    for (int j = 0; j < 64; ++j) s = fmaf(Wc[t * 64 + j], bl2[j], s);
    bfv[t] = s;
  }
}

// ---------- transform1: t1 = x@Wl1^T (bf16), r1 = x@Wr1^T + b_l1 (f32) ----
__global__ __launch_bounds__(512) void transform1_kernel(
    const float* __restrict__ x, const float* __restrict__ Wl,
    const float* __restrict__ bl, const float* __restrict__ Wr,
    unsigned short* __restrict__ t1, float* __restrict__ r1) {
  __shared__ float4 WlT4[64 * ROWP];
  __shared__ float4 WrT4[64 * ROWP];
  int tid = threadIdx.x;
  for (int i = tid; i < 1024; i += 512) {
    int k = i >> 4, j4s = i & 15;
    int slot = (k >> 4) + (k & 15) * 4;
    float4 wa, wb;
    wa.x = Wl[(4 * j4s + 0) * D + k];
    wa.y = Wl[(4 * j4s + 1) * D + k];
    wa.z = Wl[(4 * j4s + 2) * D + k];
    wa.w = Wl[(4 * j4s + 3) * D + k];
    wb.x = Wr[(4 * j4s + 0) * D + k];
    wb.y = Wr[(4 * j4s + 1) * D + k];
    wb.z = Wr[(4 * j4s + 2) * D + k];
    wb.w = Wr[(4 * j4s + 3) * D + k];
    WlT4[slot * ROWP + j4s] = wa;
    WrT4[slot * ROWP + j4s] = wb;
  }
  __syncthreads();

  int lane = tid & 63;
  int q = lane >> 4, j4 = lane & 15;
  float4 blr = ((const float4*)bl)[j4];

  int nWaves = (gridDim.x * 512) >> 6;
  int gw = (blockIdx.x * 512 + tid) >> 6;

  for (int n = gw; n < N_NODES; n += nWaves) {
    float4 xv = ((const float4*)x)[(size_t)n * 16 + j4];
    float4 o1 = make_float4(0.f, 0.f, 0.f, 0.f);
    float4 o2 = make_float4(0.f, 0.f, 0.f, 0.f);
#pragma unroll
    for (int kg = 0; kg < 4; ++kg) {
#pragma unroll
      for (int kc = 0; kc < 4; ++kc) {
        int slot = q + 16 * kg + 4 * kc;
        float4 wl4 = WlT4[slot * ROWP + j4];
        float4 wr4 = WrT4[slot * ROWP + j4];
        float xc = (kc == 0) ? xv.x : (kc == 1) ? xv.y : (kc == 2) ? xv.z : xv.w;
        float xkv = __shfl(xc, q * 4 + kg);
        o1.x = fmaf(xkv, wl4.x, o1.x); o1.y = fmaf(xkv, wl4.y, o1.y);
        o1.z = fmaf(xkv, wl4.z, o1.z); o1.w = fmaf(xkv, wl4.w, o1.w);
        o2.x = fmaf(xkv, wr4.x, o2.x); o2.y = fmaf(xkv, wr4.y, o2.y);
        o2.z = fmaf(xkv, wr4.z, o2.z); o2.w = fmaf(xkv, wr4.w, o2.w);
      }
    }
    o1.x += __shfl_xor(o1.x, 16); o1.x += __shfl_xor(o1.x, 32);
    o1.y += __shfl_xor(o1.y, 16); o1.y += __shfl_xor(o1.y, 32);
    o1.z += __shfl_xor(o1.z, 16); o1.z += __shfl_xor(o1.z, 32);
    o1.w += __shfl_xor(o1.w, 16); o1.w += __shfl_xor(o1.w, 32);
    o2.x += __shfl_xor(o2.x, 16); o2.x += __shfl_xor(o2.x, 32);
    o2.y += __shfl_xor(o2.y, 16); o2.y += __shfl_xor(o2.y, 32);
    o2.z += __shfl_xor(o2.z, 16); o2.z += __shfl_xor(o2.z, 32);
    o2.w += __shfl_xor(o2.w, 16); o2.w += __shfl_xor(o2.w, 32);
    o2.x += blr.x; o2.y += blr.y; o2.z += blr.z; o2.w += blr.w;
    if (lane < 16) {
      uint2 p;
      p.x = f2bf(o1.x) | (f2bf(o1.y) << 16);
      p.y = f2bf(o1.z) | (f2bf(o1.w) << 16);
      ((uint2*)(t1 + (size_t)n * 64))[j4] = p;
      ((float4*)r1)[(size_t)n * 16 + j4] = o2;
    }
  }
}

// ---------- gather1: CSR mean of t1, + r1, relu, project to 2+2 ----------
#define ACC8(v, m)                       \
  acc[0] = fmaf(BF_LO(v.x), m, acc[0]);  \
  acc[1] = fmaf(BF_HI(v.x), m, acc[1]);  \
  acc[2] = fmaf(BF_LO(v.y), m, acc[2]);  \
  acc[3] = fmaf(BF_HI(v.y), m, acc[3]);  \
  acc[4] = fmaf(BF_LO(v.z), m, acc[4]);  \
  acc[5] = fmaf(BF_HI(v.z), m, acc[5]);  \
  acc[6] = fmaf(BF_LO(v.w), m, acc[6]);  \
  acc[7] = fmaf(BF_HI(v.w), m, acc[7]);

__global__ __launch_bounds__(512) void gather1_kernel(
    const int* __restrict__ rowstart, const int* __restrict__ degI,
    const int* __restrict__ adj, const unsigned short* __restrict__ t1,
    const float* __restrict__ r1, const float* __restrict__ A2,
    const float* __restrict__ B2, float2* __restrict__ g2,
    float2* __restrict__ s2, int nE) {
  int tid = threadIdx.x, lane = tid & 63;
  int o = lane >> 3, j8 = lane & 7;
  float pa0[8], pa1[8], pb0[8], pb1[8];
  {
    float4 a = ((const float4*)A2)[j8 * 2], b = ((const float4*)A2)[j8 * 2 + 1];
    pa0[0] = a.x; pa0[1] = a.y; pa0[2] = a.z; pa0[3] = a.w;
    pa0[4] = b.x; pa0[5] = b.y; pa0[6] = b.z; pa0[7] = b.w;
    a = ((const float4*)A2)[16 + j8 * 2]; b = ((const float4*)A2)[16 + j8 * 2 + 1];
    pa1[0] = a.x; pa1[1] = a.y; pa1[2] = a.z; pa1[3] = a.w;
    pa1[4] = b.x; pa1[5] = b.y; pa1[6] = b.z; pa1[7] = b.w;
    a = ((const float4*)B2)[j8 * 2]; b = ((const float4*)B2)[j8 * 2 + 1];
    pb0[0] = a.x; pb0[1] = a.y; pb0[2] = a.z; pb0[3] = a.w;
    pb0[4] = b.x; pb0[5] = b.y; pb0[6] = b.z; pb0[7] = b.w;
    a = ((const float4*)B2)[16 + j8 * 2]; b = ((const float4*)B2)[16 + j8 * 2 + 1];
    pb1[0] = a.x; pb1[1] = a.y; pb1[2] = a.z; pb1[3] = a.w;
    pb1[4] = b.x; pb1[5] = b.y; pb1[6] = b.z; pb1[7] = b.w;
  }

  int gw = (blockIdx.x * 512 + tid) >> 6;
  int nWaves = (gridDim.x * 512) >> 6;

  for (int n = gw; n < N_NODES; n += nWaves) {
    int rs = rowstart[n], dg = degI[n];
    float acc[8] = {0.f, 0.f, 0.f, 0.f, 0.f, 0.f, 0.f, 0.f};
    for (int base = 0; base < dg; base += 64) {
      int cnt = min(dg - base, 64);
      int a = adj[min(rs + base + lane, nE - 1)];
      for (int t = 0; t < cnt; t += 16) {
        int el0 = t + o, el1 = t + 8 + o;  // <= 63
        int nb0 = __shfl(a, el0);
        int nb1 = __shfl(a, el1);
        bool ok0 = el0 < cnt, ok1 = el1 < cnt;
        nb0 = ok0 ? nb0 : n;
        nb1 = ok1 ? nb1 : n;
        uint4 v0 = *(const uint4*)(t1 + (size_t)nb0 * 64 + j8 * 8);
        uint4 v1 = *(const uint4*)(t1 + (size_t)nb1 * 64 + j8 * 8);
        float m0 = ok0 ? 1.f : 0.f, m1 = ok1 ? 1.f : 0.f;
        ACC8(v0, m0)
        ACC8(v1, m1)
      }
    }
#pragma unroll
    for (int jj = 0; jj < 8; ++jj) {
      acc[jj] += __shfl_xor(acc[jj], 8);
      acc[jj] += __shfl_xor(acc[jj], 16);
      acc[jj] += __shfl_xor(acc[jj], 32);
    }
    float inv = 1.f / (float)max(dg, 1);
    float4 ra = ((const float4*)r1)[(size_t)n * 16 + j8 * 2];
    float4 rb = ((const float4*)r1)[(size_t)n * 16 + j8 * 2 + 1];
    float h[8];
    h[0] = fmaxf(fmaf(acc[0], inv, ra.x), 0.f);
    h[1] = fmaxf(fmaf(acc[1], inv, ra.y), 0.f);
    h[2] = fmaxf(fmaf(acc[2], inv, ra.z), 0.f);
    h[3] = fmaxf(fmaf(acc[3], inv, ra.w), 0.f);
    h[4] = fmaxf(fmaf(acc[4], inv, rb.x), 0.f);
    h[5] = fmaxf(fmaf(acc[5], inv, rb.y), 0.f);
    h[6] = fmaxf(fmaf(acc[6], inv, rb.z), 0.f);
    h[7] = fmaxf(fmaf(acc[7], inv, rb.w), 0.f);
    float d0 = 0.f, d1 = 0.f, d2 = 0.f, d3 = 0.f;
#pragma unroll
    for (int i = 0; i < 8; ++i) {
      d0 = fmaf(h[i], pa0[i], d0);
      d1 = fmaf(h[i], pa1[i], d1);
      d2 = fmaf(h[i], pb0[i], d2);
      d3 = fmaf(h[i], pb1[i], d3);
    }
    d0 += __shfl_xor(d0, 1); d0 += __shfl_xor(d0, 2); d0 += __shfl_xor(d0, 4);
    d1 += __shfl_xor(d1, 1); d1 += __shfl_xor(d1, 2); d1 += __shfl_xor(d1, 4);
    d2 += __shfl_xor(d2, 1); d2 += __shfl_xor(d2, 2); d2 += __shfl_xor(d2, 4);
    d3 += __shfl_xor(d3, 1); d3 += __shfl_xor(d3, 2); d3 += __shfl_xor(d3, 4);
    if (lane == 0) {
      g2[n] = make_float2(d0, d1);
      s2[n] = make_float2(d2, d3);
    }
  }
}

// ---------- gather2: out[n] = mean_j(g2[j]) + s2[n] + bf ----------
__global__ __launch_bounds__(256) void gather2_kernel(
    const int* __restrict__ rowstart, const int* __restrict__ degI,
    const int* __restrict__ adj, const float2* __restrict__ g2,
    const float2* __restrict__ s2, const float* __restrict__ bfv,
    float* __restrict__ out, int nE) {
  int tid = threadIdx.x, lane = tid & 63;
  int q = lane >> 4, l16 = lane & 15;
  float bf0 = bfv[0], bf1 = bfv[1];
  int gq = ((blockIdx.x * 256 + tid) >> 6) * 4 + q;
  int strideN = ((gridDim.x * 256) >> 6) * 4;
  for (int n = gq; n < N_NODES; n += strideN) {
    int rs = rowstart[n], dg = degI[n];
    float s0 = 0.f, s1 = 0.f;
    for (int base = 0; base < dg; base += 16) {
      int e = base + l16;
      int a = adj[min(rs + e, nE - 1)];
      float2 v = g2[a];
      float m = (e < dg) ? 1.f : 0.f;
      s0 = fmaf(v.x, m, s0);
      s1 = fmaf(v.y, m, s1);
    }
    s0 += __shfl_xor(s0, 1); s0 += __shfl_xor(s0, 2);
    s0 += __shfl_xor(s0, 4); s0 += __shfl_xor(s0, 8);
    s1 += __shfl_xor(s1, 1); s1 += __shfl_xor(s1, 2);
    s1 += __shfl_xor(s1, 4); s1 += __shfl_xor(s1, 8);
    if (l16 == 0) {
      float inv = 1.f / (float)max(dg, 1);
      float2 sv = s2[n];
      out[(size_t)n * 2 + 0] = fmaf(s0, inv, sv.x) + bf0;
      out[(size_t)n * 2 + 1] = fmaf(s1, inv, sv.y) + bf1;
    }
  }
}

extern "C" void kernel_launch(void* const* d_in, const int* in_sizes, int n_in,
                              void* d_out, int out_size, void* d_ws,
                              size_t ws_size, hipStream_t stream) {
  const float* x   = (const float*)d_in[0];
  const int*   ei  = (const int*)d_in[1];
  const float* Wl1 = (const float*)d_in[2];
  const float* bl1 = (const float*)d_in[3];
  const float* Wr1 = (const float*)d_in[4];
  const float* Wl2 = (const float*)d_in[5];
  const float* bl2 = (const float*)d_in[6];
  const float* Wr2 = (const float*)d_in[7];
  const float* Wc  = (const float*)d_in[8];
  const float* bc  = (const float*)d_in[9];
  float* out = (float*)d_out;

  int nE = in_sizes[1] / 2;
  const int* src = ei;
  const int* dst = ei + nE;

  // Workspace (~46.4 MB): r1 f32[N*64] (aliased by pairs uint2[E] during CSR
  // build; transform1 runs after passD) | t1 bf16[N*64] | g2,s2 f2[N] |
  // A2/B2/bf | degI,rowstart [N] | gcnt[GCNT_N] | csum[1024] | adj[E]
  float* r1 = (float*)d_ws;
  uint2* pairs = (uint2*)d_ws;  // alias: dead before transform1 writes r1
  unsigned short* t1 = (unsigned short*)(r1 + (size_t)N_NODES * D);
  float2* g2 = (float2*)(t1 + (size_t)N_NODES * D);
  float2* s2 = g2 + N_NODES;
  float* A2 = (float*)(s2 + N_NODES);
  float* B2 = A2 + 128;
  float* bfv = B2 + 128;
  int* degI = (int*)(bfv + 4);
  int* rowstart = degI + N_NODES;
  int* gcnt = rowstart + N_NODES;
  int* csum = gcnt + GCNT_N;
  int* adj = csum + 1024;

  int ec = (nE + NBLK_A - 1) / NBLK_A;  // edges per count/place block

  passA_count<<<NBLK_A, 256, 0, stream>>>(dst, gcnt, nE, ec);
  gscan_p1<<<NCHUNK, 256, 0, stream>>>(gcnt, csum);
  gscan_p2<<<1, 1024, 0, stream>>>(csum, NCHUNK);
  gscan_p3<<<NCHUNK, 256, 0, stream>>>(gcnt, csum);
  passC_place<<<NBLK_A, 256, 0, stream>>>(src, dst, gcnt, pairs, nE, ec);
  passD_csr<<<NBUCK, 256, 0, stream>>>(pairs, gcnt, rowstart, degI, adj, nE);

  wfold_kernel<<<1, 128, 0, stream>>>(Wc, Wl2, Wr2, bl2, bc, A2, B2, bfv);
  transform1_kernel<<<1024, 512, 0, stream>>>(x, Wl1, bl1, Wr1, t1, r1);
  gather1_kernel<<<1024, 512, 0, stream>>>(rowstart, degI, adj, t1, r1, A2,
                                           B2, g2, s2, nE);
  gather2_kernel<<<512, 256, 0, stream>>>(rowstart, degI, adj, g2, s2, bfv,
                                          out, nE);
}

// Round 9
// 149.021 us; speedup vs baseline: 11.1411x; 1.2955x over previous
//
#include <hip/hip_runtime.h>

#define N_NODES 100000
#define D 64
#define NBUCK 391         // buckets of 256 nodes: dst>>8
#define NBLK_A 512        // blocks in count/place passes
#define GCNT_N (NBUCK * NBLK_A)            // 200192
#define NCHUNK ((GCNT_N + 255) / 256)      // 782 scan chunks
#define NTILE (N_NODES / 32)               // 3125 exact

typedef __attribute__((ext_vector_type(8))) short short8;
typedef __attribute__((ext_vector_type(16))) float f32x16;
union Pack8 { uint4 u; short8 s; };

__device__ __forceinline__ unsigned f2bf(float f) {  // RNE float->bf16 bits
  unsigned u = __float_as_uint(f);
  return (u + 0x7fffu + ((u >> 16) & 1u)) >> 16;
}
#define BF_LO(u) __uint_as_float(((unsigned)(u)) << 16)
#define BF_HI(u) __uint_as_float(((unsigned)(u)) & 0xffff0000u)

// ---------- counting-sort CSR build (LDS atomics only) ----------

__global__ __launch_bounds__(256) void passA_count(const int* __restrict__ dst,
                                                   int* __restrict__ gcnt,
                                                   int nE, int ec) {
  __shared__ int cnt[NBUCK];
  int t = threadIdx.x, blk = blockIdx.x;
  for (int i = t; i < NBUCK; i += 256) cnt[i] = 0;
  __syncthreads();
  int e0 = blk * ec, e1 = min(e0 + ec, nE);
  for (int e = e0 + t; e < e1; e += 256) atomicAdd(&cnt[dst[e] >> 8], 1);
  __syncthreads();
  for (int b = t; b < NBUCK; b += 256) gcnt[b * NBLK_A + blk] = cnt[b];
}

__global__ void gscan_p1(const int* __restrict__ g, int* __restrict__ csum) {
  int t = threadIdx.x, b = blockIdx.x;
  int i = b * 256 + t;
  int v = (i < GCNT_N) ? g[i] : 0;
  for (int off = 32; off; off >>= 1) v += __shfl_down(v, off);
  __shared__ int ws4[4];
  if ((t & 63) == 0) ws4[t >> 6] = v;
  __syncthreads();
  if (t == 0) csum[b] = ws4[0] + ws4[1] + ws4[2] + ws4[3];
}

__global__ void gscan_p2(int* __restrict__ csum, int nB) {
  __shared__ int s[1024];
  int t = threadIdx.x;
  int orig = (t < nB) ? csum[t] : 0;
  s[t] = orig;
  __syncthreads();
  for (int off = 1; off < 1024; off <<= 1) {
    int v = (t >= off) ? s[t - off] : 0;
    __syncthreads();
    s[t] += v;
    __syncthreads();
  }
  if (t < nB) csum[t] = s[t] - orig;  // exclusive block offsets
}

__global__ void gscan_p3(int* __restrict__ g, const int* __restrict__ csum) {
  __shared__ int s[256];
  int t = threadIdx.x, b = blockIdx.x;
  int i = b * 256 + t;
  int d = (i < GCNT_N) ? g[i] : 0;
  s[t] = d;
  __syncthreads();
  for (int off = 1; off < 256; off <<= 1) {
    int v = (t >= off) ? s[t - off] : 0;
    __syncthreads();
    s[t] += v;
    __syncthreads();
  }
  if (i < GCNT_N) g[i] = s[t] - d + csum[b];  // exclusive
}

__global__ __launch_bounds__(256) void passC_place(const int* __restrict__ src,
                                                   const int* __restrict__ dst,
                                                   const int* __restrict__ S,
                                                   uint2* __restrict__ pairs,
                                                   int nE, int ec) {
  __shared__ int cur[NBUCK];
  int t = threadIdx.x, blk = blockIdx.x;
  for (int b = t; b < NBUCK; b += 256) cur[b] = S[b * NBLK_A + blk];
  __syncthreads();
  int e0 = blk * ec, e1 = min(e0 + ec, nE);
  for (int e = e0 + t; e < e1; e += 256) {
    int d = dst[e];
    int p = atomicAdd(&cur[d >> 8], 1);
    pairs[p] = make_uint2((unsigned)d, (unsigned)src[e]);
  }
}

__global__ __launch_bounds__(256) void passD_csr(const uint2* __restrict__ pairs,
                                                 const int* __restrict__ S,
                                                 int* __restrict__ rowstart,
                                                 int* __restrict__ degI,
                                                 int* __restrict__ adj, int nE) {
  __shared__ int lh[256];
  __shared__ int sc[256];
  __shared__ int cur[256];
  int t = threadIdx.x, b = blockIdx.x;
  int base = S[b * NBLK_A];
  int end = (b == NBUCK - 1) ? nE : S[(b + 1) * NBLK_A];
  lh[t] = 0;
  __syncthreads();
  for (int p = base + t; p < end; p += 256) atomicAdd(&lh[pairs[p].x & 255], 1);
  __syncthreads();
  int d = lh[t];
  sc[t] = d;
  __syncthreads();
  for (int off = 1; off < 256; off <<= 1) {
    int v = (t >= off) ? sc[t - off] : 0;
    __syncthreads();
    sc[t] += v;
    __syncthreads();
  }
  int ex = sc[t] - d;  // exclusive local offset
  int node = b * 256 + t;
  if (node < N_NODES) {
    rowstart[node] = base + ex;
    degI[node] = d;
  }
  cur[t] = base + ex;
  __syncthreads();
  for (int p = base + t; p < end; p += 256) {
    uint2 e = pairs[p];
    int slot = atomicAdd(&cur[e.x & 255], 1);
    adj[slot] = (int)e.y;
  }
}

// ---------- Fold classifier through layer 2 ----------
__global__ void wfold_kernel(const float* __restrict__ Wc,
                             const float* __restrict__ Wl2,
                             const float* __restrict__ Wr2,
                             const float* __restrict__ bl2,
                             const float* __restrict__ bc,
                             float* __restrict__ A2, float* __restrict__ B2,
                             float* __restrict__ bfv) {
  int t = threadIdx.x;  // 128 threads
  int c = t >> 6, k = t & 63;
  float sa = 0.f, sb = 0.f;
  for (int j = 0; j < 64; ++j) {
    float w = Wc[c * 64 + j];
    sa = fmaf(w, Wl2[j * 64 + k], sa);
    sb = fmaf(w, Wr2[j * 64 + k], sb);
  }
  A2[c * 64 + k] = sa;
  B2[c * 64 + k] = sb;
  if (t < 2) {
    float s = bc[t];
    for (int j = 0; j < 64; ++j) s = fmaf(Wc[t * 64 + j], bl2[j], s);
    bfv[t] = s;
  }
}

// ---------- wprep: wcat = bf16(concat(Wl1, Wr1)) [128 x 64] ----------
__global__ void wprep_kernel(const float* __restrict__ Wl,
                             const float* __restrict__ Wr,
                             unsigned short* __restrict__ wcat) {
  int i = blockIdx.x * 256 + threadIdx.x;  // 8192 total
  if (i < 4096) wcat[i] = (unsigned short)f2bf(Wl[i]);
  else if (i < 8192) wcat[i] = (unsigned short)f2bf(Wr[i - 4096]);
}

// ---------- transform_mfma: [t1|r1] = x @ [Wl1|Wr1]^T via 32x32x16 bf16 ----
// Wave-per-32-node-tile. A = W' rows (features), B = x columns (nodes):
// D[j][n]. C/D layout (m74/m101): col(=node)=lane&31,
// row(=j)=(reg&3)+8*(reg>>2)+4*(lane>>5) -> per-lane one node, contiguous
// 4-j runs -> uint2 (t1 bf16) / float4 (r1 + bias) stores.
__global__ __launch_bounds__(256) void transform_mfma(
    const float* __restrict__ x, const unsigned short* __restrict__ wcat,
    const float* __restrict__ bl, unsigned short* __restrict__ t1,
    float* __restrict__ r1) {
  int tid = threadIdx.x, lane = tid & 63;
  int l31 = lane & 31, hi = lane >> 5;

  // A-frags: lane holds W'[jt*32 + l31][kk*16 + 8*hi .. +8)  (8 bf16 = 16B)
  short8 af[4][4];
#pragma unroll
  for (int jt = 0; jt < 4; ++jt)
#pragma unroll
    for (int kk = 0; kk < 4; ++kk)
      af[jt][kk] = *(const short8*)(wcat + (jt * 32 + l31) * 64 + kk * 16 + 8 * hi);

  const f32x16 Z = {0.f, 0.f, 0.f, 0.f, 0.f, 0.f, 0.f, 0.f,
                    0.f, 0.f, 0.f, 0.f, 0.f, 0.f, 0.f, 0.f};
  const float4* x4 = (const float4*)x;

  int gw = (blockIdx.x * 256 + tid) >> 6;
  int nW = (gridDim.x * 256) >> 6;

  for (int tile = gw; tile < NTILE; tile += nW) {
    int base = tile * 32;
    int node = base + l31;
    f32x16 acc[4] = {Z, Z, Z, Z};
#pragma unroll
    for (int kk = 0; kk < 4; ++kk) {
      // B-frag: x[node][kk*16 + 8*hi .. +8) as bf16
      float4 fa = x4[(size_t)node * 16 + kk * 4 + 2 * hi];
      float4 fb = x4[(size_t)node * 16 + kk * 4 + 2 * hi + 1];
      Pack8 pk;
      pk.u.x = f2bf(fa.x) | (f2bf(fa.y) << 16);
      pk.u.y = f2bf(fa.z) | (f2bf(fa.w) << 16);
      pk.u.z = f2bf(fb.x) | (f2bf(fb.y) << 16);
      pk.u.w = f2bf(fb.z) | (f2bf(fb.w) << 16);
      acc[0] = __builtin_amdgcn_mfma_f32_32x32x16_bf16(af[0][kk], pk.s, acc[0], 0, 0, 0);
      acc[1] = __builtin_amdgcn_mfma_f32_32x32x16_bf16(af[1][kk], pk.s, acc[1], 0, 0, 0);
      acc[2] = __builtin_amdgcn_mfma_f32_32x32x16_bf16(af[2][kk], pk.s, acc[2], 0, 0, 0);
      acc[3] = __builtin_amdgcn_mfma_f32_32x32x16_bf16(af[3][kk], pk.s, acc[3], 0, 0, 0);
    }
    // epilogue: t1 from jt 0,1 (bf16), r1 from jt 2,3 (f32 + bias)
#pragma unroll
    for (int jt = 0; jt < 2; ++jt)
#pragma unroll
      for (int rg = 0; rg < 4; ++rg) {
        int j0 = jt * 32 + 8 * rg + 4 * hi;
        uint2 p;
        p.x = f2bf(acc[jt][4 * rg + 0]) | (f2bf(acc[jt][4 * rg + 1]) << 16);
        p.y = f2bf(acc[jt][4 * rg + 2]) | (f2bf(acc[jt][4 * rg + 3]) << 16);
        *(uint2*)(t1 + (size_t)node * 64 + j0) = p;
      }
#pragma unroll
    for (int jt = 2; jt < 4; ++jt)
#pragma unroll
      for (int rg = 0; rg < 4; ++rg) {
        int j0 = (jt - 2) * 32 + 8 * rg + 4 * hi;
        float4 bv = ((const float4*)bl)[j0 >> 2];
        float4 o;
        o.x = acc[jt][4 * rg + 0] + bv.x;
        o.y = acc[jt][4 * rg + 1] + bv.y;
        o.z = acc[jt][4 * rg + 2] + bv.z;
        o.w = acc[jt][4 * rg + 3] + bv.w;
        *(float4*)(r1 + (size_t)node * 64 + j0) = o;
      }
  }
}

// ---------- gather1: CSR mean of t1, + r1, relu, project to 2+2 ----------
#define ACC8(v, m)                       \
  acc[0] = fmaf(BF_LO(v.x), m, acc[0]);  \
  acc[1] = fmaf(BF_HI(v.x), m, acc[1]);  \
  acc[2] = fmaf(BF_LO(v.y), m, acc[2]);  \
  acc[3] = fmaf(BF_HI(v.y), m, acc[3]);  \
  acc[4] = fmaf(BF_LO(v.z), m, acc[4]);  \
  acc[5] = fmaf(BF_HI(v.z), m, acc[5]);  \
  acc[6] = fmaf(BF_LO(v.w), m, acc[6]);  \
  acc[7] = fmaf(BF_HI(v.w), m, acc[7]);

__global__ __launch_bounds__(512) void gather1_kernel(
    const int* __restrict__ rowstart, const int* __restrict__ degI,
    const int* __restrict__ adj, const unsigned short* __restrict__ t1,
    const float* __restrict__ r1, const float* __restrict__ A2,
    const float* __restrict__ B2, float2* __restrict__ g2,
    float2* __restrict__ s2, int nE) {
  int tid = threadIdx.x, lane = tid & 63;
  int o = lane >> 3, j8 = lane & 7;
  float pa0[8], pa1[8], pb0[8], pb1[8];
  {
    float4 a = ((const float4*)A2)[j8 * 2], b = ((const float4*)A2)[j8 * 2 + 1];
    pa0[0] = a.x; pa0[1] = a.y; pa0[2] = a.z; pa0[3] = a.w;
    pa0[4] = b.x; pa0[5] = b.y; pa0[6] = b.z; pa0[7] = b.w;
    a = ((const float4*)A2)[16 + j8 * 2]; b = ((const float4*)A2)[16 + j8 * 2 + 1];
    pa1[0] = a.x; pa1[1] = a.y; pa1[2] = a.z; pa1[3] = a.w;
    pa1[4] = b.x; pa1[5] = b.y; pa1[6] = b.z; pa1[7] = b.w;
    a = ((const float4*)B2)[j8 * 2]; b = ((const float4*)B2)[j8 * 2 + 1];
    pb0[0] = a.x; pb0[1] = a.y; pb0[2] = a.z; pb0[3] = a.w;
    pb0[4] = b.x; pb0[5] = b.y; pb0[6] = b.z; pb0[7] = b.w;
    a = ((const float4*)B2)[16 + j8 * 2]; b = ((const float4*)B2)[16 + j8 * 2 + 1];
    pb1[0] = a.x; pb1[1] = a.y; pb1[2] = a.z; pb1[3] = a.w;
    pb1[4] = b.x; pb1[5] = b.y; pb1[6] = b.z; pb1[7] = b.w;
  }

  int gw = (blockIdx.x * 512 + tid) >> 6;
  int nWaves = (gridDim.x * 512) >> 6;

  for (int n = gw; n < N_NODES; n += nWaves) {
    int rs = rowstart[n], dg = degI[n];
    float acc[8] = {0.f, 0.f, 0.f, 0.f, 0.f, 0.f, 0.f, 0.f};
    for (int base = 0; base < dg; base += 64) {
      int cnt = min(dg - base, 64);
      int a = adj[min(rs + base + lane, nE - 1)];
      for (int t = 0; t < cnt; t += 16) {
        int el0 = t + o, el1 = t + 8 + o;  // <= 63
        int nb0 = __shfl(a, el0);
        int nb1 = __shfl(a, el1);
        bool ok0 = el0 < cnt, ok1 = el1 < cnt;
        nb0 = ok0 ? nb0 : n;
        nb1 = ok1 ? nb1 : n;
        uint4 v0 = *(const uint4*)(t1 + (size_t)nb0 * 64 + j8 * 8);
        uint4 v1 = *(const uint4*)(t1 + (size_t)nb1 * 64 + j8 * 8);
        float m0 = ok0 ? 1.f : 0.f, m1 = ok1 ? 1.f : 0.f;
        ACC8(v0, m0)
        ACC8(v1, m1)
      }
    }
#pragma unroll
    for (int jj = 0; jj < 8; ++jj) {
      acc[jj] += __shfl_xor(acc[jj], 8);
      acc[jj] += __shfl_xor(acc[jj], 16);
      acc[jj] += __shfl_xor(acc[jj], 32);
    }
    float inv = 1.f / (float)max(dg, 1);
    float4 ra = ((const float4*)r1)[(size_t)n * 16 + j8 * 2];
    float4 rb = ((const float4*)r1)[(size_t)n * 16 + j8 * 2 + 1];
    float h[8];
    h[0] = fmaxf(fmaf(acc[0], inv, ra.x), 0.f);
    h[1] = fmaxf(fmaf(acc[1], inv, ra.y), 0.f);
    h[2] = fmaxf(fmaf(acc[2], inv, ra.z), 0.f);
    h[3] = fmaxf(fmaf(acc[3], inv, ra.w), 0.f);
    h[4] = fmaxf(fmaf(acc[4], inv, rb.x), 0.f);
    h[5] = fmaxf(fmaf(acc[5], inv, rb.y), 0.f);
    h[6] = fmaxf(fmaf(acc[6], inv, rb.z), 0.f);
    h[7] = fmaxf(fmaf(acc[7], inv, rb.w), 0.f);
    float d0 = 0.f, d1 = 0.f, d2 = 0.f, d3 = 0.f;
#pragma unroll
    for (int i = 0; i < 8; ++i) {
      d0 = fmaf(h[i], pa0[i], d0);
      d1 = fmaf(h[i], pa1[i], d1);
      d2 = fmaf(h[i], pb0[i], d2);
      d3 = fmaf(h[i], pb1[i], d3);
    }
    d0 += __shfl_xor(d0, 1); d0 += __shfl_xor(d0, 2); d0 += __shfl_xor(d0, 4);
    d1 += __shfl_xor(d1, 1); d1 += __shfl_xor(d1, 2); d1 += __shfl_xor(d1, 4);
    d2 += __shfl_xor(d2, 1); d2 += __shfl_xor(d2, 2); d2 += __shfl_xor(d2, 4);
    d3 += __shfl_xor(d3, 1); d3 += __shfl_xor(d3, 2); d3 += __shfl_xor(d3, 4);
    if (lane == 0) {
      g2[n] = make_float2(d0, d1);
      s2[n] = make_float2(d2, d3);
    }
  }
}

// ---------- gather2: out[n] = mean_j(g2[j]) + s2[n] + bf ----------
__global__ __launch_bounds__(256) void gather2_kernel(
    const int* __restrict__ rowstart, const int* __restrict__ degI,
    const int* __restrict__ adj, const float2* __restrict__ g2,
    const float2* __restrict__ s2, const float* __restrict__ bfv,
    float* __restrict__ out, int nE) {
  int tid = threadIdx.x, lane = tid & 63;
  int q = lane >> 4, l16 = lane & 15;
  float bf0 = bfv[0], bf1 = bfv[1];
  int gq = ((blockIdx.x * 256 + tid) >> 6) * 4 + q;
  int strideN = ((gridDim.x * 256) >> 6) * 4;
  for (int n = gq; n < N_NODES; n += strideN) {
    int rs = rowstart[n], dg = degI[n];
    float s0 = 0.f, s1 = 0.f;
    for (int base = 0; base < dg; base += 16) {
      int e = base + l16;
      int a = adj[min(rs + e, nE - 1)];
      float2 v = g2[a];
      float m = (e < dg) ? 1.f : 0.f;
      s0 = fmaf(v.x, m, s0);
      s1 = fmaf(v.y, m, s1);
    }
    s0 += __shfl_xor(s0, 1); s0 += __shfl_xor(s0, 2);
    s0 += __shfl_xor(s0, 4); s0 += __shfl_xor(s0, 8);
    s1 += __shfl_xor(s1, 1); s1 += __shfl_xor(s1, 2);
    s1 += __shfl_xor(s1, 4); s1 += __shfl_xor(s1, 8);
    if (l16 == 0) {
      float inv = 1.f / (float)max(dg, 1);
      float2 sv = s2[n];
      out[(size_t)n * 2 + 0] = fmaf(s0, inv, sv.x) + bf0;
      out[(size_t)n * 2 + 1] = fmaf(s1, inv, sv.y) + bf1;
    }
  }
}

extern "C" void kernel_launch(void* const* d_in, const int* in_sizes, int n_in,
                              void* d_out, int out_size, void* d_ws,
                              size_t ws_size, hipStream_t stream) {
  const float* x   = (const float*)d_in[0];
  const int*   ei  = (const int*)d_in[1];
  const float* Wl1 = (const float*)d_in[2];
  const float* bl1 = (const float*)d_in[3];
  const float* Wr1 = (const float*)d_in[4];
  const float* Wl2 = (const float*)d_in[5];
  const float* bl2 = (const float*)d_in[6];
  const float* Wr2 = (const float*)d_in[7];
  const float* Wc  = (const float*)d_in[8];
  const float* bc  = (const float*)d_in[9];
  float* out = (float*)d_out;

  int nE = in_sizes[1] / 2;
  const int* src = ei;
  const int* dst = ei + nE;

  // Workspace (~46.4 MB): r1 f32[N*64] (aliased by pairs uint2[E] during CSR
  // build; transform runs after passD) | t1 bf16[N*64] | g2,s2 f2[N] |
  // A2/B2/bf | wcat bf16[8192] | degI,rowstart [N] | gcnt | csum | adj[E]
  float* r1 = (float*)d_ws;
  uint2* pairs = (uint2*)d_ws;  // alias: dead before transform writes r1
  unsigned short* t1 = (unsigned short*)(r1 + (size_t)N_NODES * D);
  float2* g2 = (float2*)(t1 + (size_t)N_NODES * D);
  float2* s2 = g2 + N_NODES;
  float* A2 = (float*)(s2 + N_NODES);
  float* B2 = A2 + 128;
  float* bfv = B2 + 128;
  unsigned short* wcat = (unsigned short*)(bfv + 4);
  int* degI = (int*)(wcat + 8192);
  int* rowstart = degI + N_NODES;
  int* gcnt = rowstart + N_NODES;
  int* csum = gcnt + GCNT_N;
  int* adj = csum + 1024;

  int ec = (nE + NBLK_A - 1) / NBLK_A;  // edges per count/place block

  passA_count<<<NBLK_A, 256, 0, stream>>>(dst, gcnt, nE, ec);
  gscan_p1<<<NCHUNK, 256, 0, stream>>>(gcnt, csum);
  gscan_p2<<<1, 1024, 0, stream>>>(csum, NCHUNK);
  gscan_p3<<<NCHUNK, 256, 0, stream>>>(gcnt, csum);
  passC_place<<<NBLK_A, 256, 0, stream>>>(src, dst, gcnt, pairs, nE, ec);
  passD_csr<<<NBUCK, 256, 0, stream>>>(pairs, gcnt, rowstart, degI, adj, nE);

  wfold_kernel<<<1, 128, 0, stream>>>(Wc, Wl2, Wr2, bl2, bc, A2, B2, bfv);
  wprep_kernel<<<32, 256, 0, stream>>>(Wl1, Wr1, wcat);
  transform_mfma<<<512, 256, 0, stream>>>(x, wcat, bl1, t1, r1);
  gather1_kernel<<<1024, 512, 0, stream>>>(rowstart, degI, adj, t1, r1, A2,
                                           B2, g2, s2, nE);
  gather2_kernel<<<512, 256, 0, stream>>>(rowstart, degI, adj, g2, s2, bfv,
                                          out, nE);
}

// Round 10
// 145.675 us; speedup vs baseline: 11.3970x; 1.0230x over previous
//
#include <hip/hip_runtime.h>

#define N_NODES 100000
#define D 64
#define NBUCK 391         // buckets of 256 nodes: dst>>8
#define NBLK_A 512        // blocks in count/place passes
#define GCNT_N (NBUCK * NBLK_A)            // 200192
#define NCHUNK ((GCNT_N + 255) / 256)      // 782 scan chunks
#define NTILE (N_NODES / 32)               // 3125 exact

typedef __attribute__((ext_vector_type(8))) short short8;
typedef __attribute__((ext_vector_type(16))) float f32x16;
union Pack8 { uint4 u; short8 s; };

__device__ __forceinline__ unsigned f2bf(float f) {  // RNE float->bf16 bits
  unsigned u = __float_as_uint(f);
  return (u + 0x7fffu + ((u >> 16) & 1u)) >> 16;
}
#define BF_LO(u) __uint_as_float(((unsigned)(u)) << 16)
#define BF_HI(u) __uint_as_float(((unsigned)(u)) & 0xffff0000u)

// ---------- counting-sort CSR build (LDS atomics only) ----------

__global__ __launch_bounds__(256) void passA_count(const int* __restrict__ dst,
                                                   int* __restrict__ gcnt,
                                                   int nE, int ec) {
  __shared__ int cnt[NBUCK];
  int t = threadIdx.x, blk = blockIdx.x;
  for (int i = t; i < NBUCK; i += 256) cnt[i] = 0;
  __syncthreads();
  int e0 = blk * ec, e1 = min(e0 + ec, nE);
  for (int e = e0 + t; e < e1; e += 256) atomicAdd(&cnt[dst[e] >> 8], 1);
  __syncthreads();
  for (int b = t; b < NBUCK; b += 256) gcnt[b * NBLK_A + blk] = cnt[b];
}

__global__ void gscan_p1(const int* __restrict__ g, int* __restrict__ csum) {
  int t = threadIdx.x, b = blockIdx.x;
  int i = b * 256 + t;
  int v = (i < GCNT_N) ? g[i] : 0;
  for (int off = 32; off; off >>= 1) v += __shfl_down(v, off);
  __shared__ int ws4[4];
  if ((t & 63) == 0) ws4[t >> 6] = v;
  __syncthreads();
  if (t == 0) csum[b] = ws4[0] + ws4[1] + ws4[2] + ws4[3];
}

__global__ void gscan_p2(int* __restrict__ csum, int nB) {
  __shared__ int s[1024];
  int t = threadIdx.x;
  int orig = (t < nB) ? csum[t] : 0;
  s[t] = orig;
  __syncthreads();
  for (int off = 1; off < 1024; off <<= 1) {
    int v = (t >= off) ? s[t - off] : 0;
    __syncthreads();
    s[t] += v;
    __syncthreads();
  }
  if (t < nB) csum[t] = s[t] - orig;  // exclusive block offsets
}

__global__ void gscan_p3(int* __restrict__ g, const int* __restrict__ csum) {
  __shared__ int s[256];
  int t = threadIdx.x, b = blockIdx.x;
  int i = b * 256 + t;
  int d = (i < GCNT_N) ? g[i] : 0;
  s[t] = d;
  __syncthreads();
  for (int off = 1; off < 256; off <<= 1) {
    int v = (t >= off) ? s[t - off] : 0;
    __syncthreads();
    s[t] += v;
    __syncthreads();
  }
  if (i < GCNT_N) g[i] = s[t] - d + csum[b];  // exclusive
}

__global__ __launch_bounds__(256) void passC_place(const int* __restrict__ src,
                                                   const int* __restrict__ dst,
                                                   const int* __restrict__ S,
                                                   uint2* __restrict__ pairs,
                                                   int nE, int ec) {
  __shared__ int cur[NBUCK];
  int t = threadIdx.x, blk = blockIdx.x;
  for (int b = t; b < NBUCK; b += 256) cur[b] = S[b * NBLK_A + blk];
  __syncthreads();
  int e0 = blk * ec, e1 = min(e0 + ec, nE);
  for (int e = e0 + t; e < e1; e += 256) {
    int d = dst[e];
    int p = atomicAdd(&cur[d >> 8], 1);
    pairs[p] = make_uint2((unsigned)d, (unsigned)src[e]);
  }
}

__global__ __launch_bounds__(256) void passD_csr(const uint2* __restrict__ pairs,
                                                 const int* __restrict__ S,
                                                 int* __restrict__ rowstart,
                                                 int* __restrict__ degI,
                                                 int* __restrict__ adj, int nE) {
  __shared__ int lh[256];
  __shared__ int sc[256];
  __shared__ int cur[256];
  int t = threadIdx.x, b = blockIdx.x;
  int base = S[b * NBLK_A];
  int end = (b == NBUCK - 1) ? nE : S[(b + 1) * NBLK_A];
  lh[t] = 0;
  __syncthreads();
  for (int p = base + t; p < end; p += 256) atomicAdd(&lh[pairs[p].x & 255], 1);
  __syncthreads();
  int d = lh[t];
  sc[t] = d;
  __syncthreads();
  for (int off = 1; off < 256; off <<= 1) {
    int v = (t >= off) ? sc[t - off] : 0;
    __syncthreads();
    sc[t] += v;
    __syncthreads();
  }
  int ex = sc[t] - d;  // exclusive local offset
  int node = b * 256 + t;
  if (node < N_NODES) {
    rowstart[node] = base + ex;
    degI[node] = d;
  }
  cur[t] = base + ex;
  __syncthreads();
  for (int p = base + t; p < end; p += 256) {
    uint2 e = pairs[p];
    int slot = atomicAdd(&cur[e.x & 255], 1);
    adj[slot] = (int)e.y;
  }
}

// ---------- Fold classifier through layer 2 ----------
__global__ void wfold_kernel(const float* __restrict__ Wc,
                             const float* __restrict__ Wl2,
                             const float* __restrict__ Wr2,
                             const float* __restrict__ bl2,
                             const float* __restrict__ bc,
                             float* __restrict__ A2, float* __restrict__ B2,
                             float* __restrict__ bfv) {
  int t = threadIdx.x;  // 128 threads
  int c = t >> 6, k = t & 63;
  float sa = 0.f, sb = 0.f;
  for (int j = 0; j < 64; ++j) {
    float w = Wc[c * 64 + j];
    sa = fmaf(w, Wl2[j * 64 + k], sa);
    sb = fmaf(w, Wr2[j * 64 + k], sb);
  }
  A2[c * 64 + k] = sa;
  B2[c * 64 + k] = sb;
  if (t < 2) {
    float s = bc[t];
    for (int j = 0; j < 64; ++j) s = fmaf(Wc[t * 64 + j], bl2[j], s);
    bfv[t] = s;
  }
}

// ---------- wprep: wcat = bf16(concat(Wl1, Wr1)) [128 x 64] ----------
__global__ void wprep_kernel(const float* __restrict__ Wl,
                             const float* __restrict__ Wr,
                             unsigned short* __restrict__ wcat) {
  int i = blockIdx.x * 256 + threadIdx.x;  // 8192 total
  if (i < 4096) wcat[i] = (unsigned short)f2bf(Wl[i]);
  else if (i < 8192) wcat[i] = (unsigned short)f2bf(Wr[i - 4096]);
}

// ---------- transform_mfma: t1 = x@Wl1^T (bf16), r1b = x@Wr1^T+b (bf16) ----
// Wave-per-32-node-tile via 32x32x16 bf16 MFMA. C/D: col(node)=lane&31,
// row(j)=(reg&3)+8*(reg>>2)+4*(lane>>5).
__global__ __launch_bounds__(256) void transform_mfma(
    const float* __restrict__ x, const unsigned short* __restrict__ wcat,
    const float* __restrict__ bl, unsigned short* __restrict__ t1,
    unsigned short* __restrict__ r1b) {
  int tid = threadIdx.x, lane = tid & 63;
  int l31 = lane & 31, hi = lane >> 5;

  short8 af[4][4];
#pragma unroll
  for (int jt = 0; jt < 4; ++jt)
#pragma unroll
    for (int kk = 0; kk < 4; ++kk)
      af[jt][kk] = *(const short8*)(wcat + (jt * 32 + l31) * 64 + kk * 16 + 8 * hi);

  const f32x16 Z = {0.f, 0.f, 0.f, 0.f, 0.f, 0.f, 0.f, 0.f,
                    0.f, 0.f, 0.f, 0.f, 0.f, 0.f, 0.f, 0.f};
  const float4* x4 = (const float4*)x;

  int gw = (blockIdx.x * 256 + tid) >> 6;
  int nW = (gridDim.x * 256) >> 6;

  for (int tile = gw; tile < NTILE; tile += nW) {
    int node = tile * 32 + l31;
    f32x16 acc[4] = {Z, Z, Z, Z};
#pragma unroll
    for (int kk = 0; kk < 4; ++kk) {
      float4 fa = x4[(size_t)node * 16 + kk * 4 + 2 * hi];
      float4 fb = x4[(size_t)node * 16 + kk * 4 + 2 * hi + 1];
      Pack8 pk;
      pk.u.x = f2bf(fa.x) | (f2bf(fa.y) << 16);
      pk.u.y = f2bf(fa.z) | (f2bf(fa.w) << 16);
      pk.u.z = f2bf(fb.x) | (f2bf(fb.y) << 16);
      pk.u.w = f2bf(fb.z) | (f2bf(fb.w) << 16);
      acc[0] = __builtin_amdgcn_mfma_f32_32x32x16_bf16(af[0][kk], pk.s, acc[0], 0, 0, 0);
      acc[1] = __builtin_amdgcn_mfma_f32_32x32x16_bf16(af[1][kk], pk.s, acc[1], 0, 0, 0);
      acc[2] = __builtin_amdgcn_mfma_f32_32x32x16_bf16(af[2][kk], pk.s, acc[2], 0, 0, 0);
      acc[3] = __builtin_amdgcn_mfma_f32_32x32x16_bf16(af[3][kk], pk.s, acc[3], 0, 0, 0);
    }
#pragma unroll
    for (int jt = 0; jt < 2; ++jt)
#pragma unroll
      for (int rg = 0; rg < 4; ++rg) {
        int j0 = jt * 32 + 8 * rg + 4 * hi;
        uint2 p;
        p.x = f2bf(acc[jt][4 * rg + 0]) | (f2bf(acc[jt][4 * rg + 1]) << 16);
        p.y = f2bf(acc[jt][4 * rg + 2]) | (f2bf(acc[jt][4 * rg + 3]) << 16);
        *(uint2*)(t1 + (size_t)node * 64 + j0) = p;
      }
#pragma unroll
    for (int jt = 2; jt < 4; ++jt)
#pragma unroll
      for (int rg = 0; rg < 4; ++rg) {
        int j0 = (jt - 2) * 32 + 8 * rg + 4 * hi;
        float4 bv = ((const float4*)bl)[j0 >> 2];
        uint2 p;
        p.x = f2bf(acc[jt][4 * rg + 0] + bv.x) |
              (f2bf(acc[jt][4 * rg + 1] + bv.y) << 16);
        p.y = f2bf(acc[jt][4 * rg + 2] + bv.z) |
              (f2bf(acc[jt][4 * rg + 3] + bv.w) << 16);
        *(uint2*)(r1b + (size_t)node * 64 + j0) = p;
      }
  }
}

// ---------- gather1: CSR mean of t1, + r1b, relu, project to 2+2 ----------
// Two nodes (n, n+1) per wave: 2 adj + 4 t1 loads in flight. adj load
// clamped to the node's live range (1 line/node, not 4). Projection
// vectors in LDS.
#define ACC8(acc, v, m)                     \
  acc[0] = fmaf(BF_LO(v.x), m, acc[0]);     \
  acc[1] = fmaf(BF_HI(v.x), m, acc[1]);     \
  acc[2] = fmaf(BF_LO(v.y), m, acc[2]);     \
  acc[3] = fmaf(BF_HI(v.y), m, acc[3]);     \
  acc[4] = fmaf(BF_LO(v.z), m, acc[4]);     \
  acc[5] = fmaf(BF_HI(v.z), m, acc[5]);     \
  acc[6] = fmaf(BF_LO(v.w), m, acc[6]);     \
  acc[7] = fmaf(BF_HI(v.w), m, acc[7]);

__global__ __launch_bounds__(512) void gather1_kernel(
    const int* __restrict__ rowstart, const int* __restrict__ degI,
    const int* __restrict__ adj, const unsigned short* __restrict__ t1,
    const unsigned short* __restrict__ r1b, const float* __restrict__ A2,
    const float* __restrict__ B2, float2* __restrict__ g2,
    float2* __restrict__ s2, int nE) {
  __shared__ float pAB[4][64];  // A2 row0, A2 row1, B2 row0, B2 row1
  int tid = threadIdx.x;
  if (tid < 256) {
    int v = tid >> 6, f = tid & 63;
    pAB[v][f] = (v < 2) ? A2[v * 64 + f] : B2[(v - 2) * 64 + f];
  }
  __syncthreads();

  int lane = tid & 63;
  int o = lane >> 3, j8 = lane & 7;
  int gw = (blockIdx.x * 512 + tid) >> 6;
  int nW = (gridDim.x * 512) >> 6;

  for (int n = gw * 2; n < N_NODES; n += nW * 2) {
    int n1 = n + 1;  // N_NODES even -> always valid
    int rs0 = rowstart[n], dg0 = degI[n];
    int rs1 = rowstart[n1], dg1 = degI[n1];
    float acc0[8] = {0.f, 0.f, 0.f, 0.f, 0.f, 0.f, 0.f, 0.f};
    float acc1[8] = {0.f, 0.f, 0.f, 0.f, 0.f, 0.f, 0.f, 0.f};
    int mx = max(dg0, dg1);
    for (int base = 0; base < mx; base += 64) {
      int cnt0 = min(max(dg0 - base, 0), 64);
      int cnt1 = min(max(dg1 - base, 0), 64);
      int a0 = adj[min(rs0 + base + ((lane < cnt0) ? lane : 0), nE - 1)];
      int a1 = adj[min(rs1 + base + ((lane < cnt1) ? lane : 0), nE - 1)];
      int mc = max(cnt0, cnt1);
      for (int t = 0; t < mc; t += 16) {
        int el0 = t + o, el1 = t + 8 + o;  // <= 63
        int b00 = __shfl(a0, el0), b01 = __shfl(a0, el1);
        int b10 = __shfl(a1, el0), b11 = __shfl(a1, el1);
        bool k00 = el0 < cnt0, k01 = el1 < cnt0;
        bool k10 = el0 < cnt1, k11 = el1 < cnt1;
        b00 = k00 ? b00 : n;  b01 = k01 ? b01 : n;
        b10 = k10 ? b10 : n1; b11 = k11 ? b11 : n1;
        uint4 v00 = *(const uint4*)(t1 + (size_t)b00 * 64 + j8 * 8);
        uint4 v01 = *(const uint4*)(t1 + (size_t)b01 * 64 + j8 * 8);
        uint4 v10 = *(const uint4*)(t1 + (size_t)b10 * 64 + j8 * 8);
        uint4 v11 = *(const uint4*)(t1 + (size_t)b11 * 64 + j8 * 8);
        float m00 = k00 ? 1.f : 0.f, m01 = k01 ? 1.f : 0.f;
        float m10 = k10 ? 1.f : 0.f, m11 = k11 ? 1.f : 0.f;
        ACC8(acc0, v00, m00)
        ACC8(acc0, v01, m01)
        ACC8(acc1, v10, m10)
        ACC8(acc1, v11, m11)
      }
    }
    // reduce over the 8 edge-slots (lane bits 3,4,5), both nodes
#pragma unroll
    for (int jj = 0; jj < 8; ++jj) {
      acc0[jj] += __shfl_xor(acc0[jj], 8);
      acc0[jj] += __shfl_xor(acc0[jj], 16);
      acc0[jj] += __shfl_xor(acc0[jj], 32);
      acc1[jj] += __shfl_xor(acc1[jj], 8);
      acc1[jj] += __shfl_xor(acc1[jj], 16);
      acc1[jj] += __shfl_xor(acc1[jj], 32);
    }
#pragma unroll
    for (int nn = 0; nn < 2; ++nn) {
      int nd = nn ? n1 : n;
      float* acc = nn ? acc1 : acc0;
      int dg = nn ? dg1 : dg0;
      float inv = 1.f / (float)max(dg, 1);
      uint4 rv = *(const uint4*)(r1b + (size_t)nd * 64 + j8 * 8);
      float h[8];
      h[0] = fmaxf(fmaf(acc[0], inv, BF_LO(rv.x)), 0.f);
      h[1] = fmaxf(fmaf(acc[1], inv, BF_HI(rv.x)), 0.f);
      h[2] = fmaxf(fmaf(acc[2], inv, BF_LO(rv.y)), 0.f);
      h[3] = fmaxf(fmaf(acc[3], inv, BF_HI(rv.y)), 0.f);
      h[4] = fmaxf(fmaf(acc[4], inv, BF_LO(rv.z)), 0.f);
      h[5] = fmaxf(fmaf(acc[5], inv, BF_HI(rv.z)), 0.f);
      h[6] = fmaxf(fmaf(acc[6], inv, BF_LO(rv.w)), 0.f);
      h[7] = fmaxf(fmaf(acc[7], inv, BF_HI(rv.w)), 0.f);
      float d0 = 0.f, d1 = 0.f, d2 = 0.f, d3 = 0.f;
#pragma unroll
      for (int i = 0; i < 8; ++i) {
        float hv = h[i];
        d0 = fmaf(hv, pAB[0][j8 * 8 + i], d0);
        d1 = fmaf(hv, pAB[1][j8 * 8 + i], d1);
        d2 = fmaf(hv, pAB[2][j8 * 8 + i], d2);
        d3 = fmaf(hv, pAB[3][j8 * 8 + i], d3);
      }
      d0 += __shfl_xor(d0, 1); d0 += __shfl_xor(d0, 2); d0 += __shfl_xor(d0, 4);
      d1 += __shfl_xor(d1, 1); d1 += __shfl_xor(d1, 2); d1 += __shfl_xor(d1, 4);
      d2 += __shfl_xor(d2, 1); d2 += __shfl_xor(d2, 2); d2 += __shfl_xor(d2, 4);
      d3 += __shfl_xor(d3, 1); d3 += __shfl_xor(d3, 2); d3 += __shfl_xor(d3, 4);
      if (lane == 0) {
        g2[nd] = make_float2(d0, d1);
        s2[nd] = make_float2(d2, d3);
      }
    }
  }
}

// ---------- gather2: out[n] = mean_j(g2[j]) + s2[n] + bf ----------
__global__ __launch_bounds__(256) void gather2_kernel(
    const int* __restrict__ rowstart, const int* __restrict__ degI,
    const int* __restrict__ adj, const float2* __restrict__ g2,
    const float2* __restrict__ s2, const float* __restrict__ bfv,
    float* __restrict__ out, int nE) {
  int tid = threadIdx.x, lane = tid & 63;
  int q = lane >> 4, l16 = lane & 15;
  float bf0 = bfv[0], bf1 = bfv[1];
  int gq = ((blockIdx.x * 256 + tid) >> 6) * 4 + q;
  int strideN = ((gridDim.x * 256) >> 6) * 4;
  for (int n = gq; n < N_NODES; n += strideN) {
    int rs = rowstart[n], dg = degI[n];
    float s0 = 0.f, s1 = 0.f;
    for (int base = 0; base < dg; base += 16) {
      int e = base + l16;
      int a = adj[min(rs + ((e < dg) ? e : 0), nE - 1)];
      float2 v = g2[a];
      float m = (e < dg) ? 1.f : 0.f;
      s0 = fmaf(v.x, m, s0);
      s1 = fmaf(v.y, m, s1);
    }
    s0 += __shfl_xor(s0, 1); s0 += __shfl_xor(s0, 2);
    s0 += __shfl_xor(s0, 4); s0 += __shfl_xor(s0, 8);
    s1 += __shfl_xor(s1, 1); s1 += __shfl_xor(s1, 2);
    s1 += __shfl_xor(s1, 4); s1 += __shfl_xor(s1, 8);
    if (l16 == 0) {
      float inv = 1.f / (float)max(dg, 1);
      float2 sv = s2[n];
      out[(size_t)n * 2 + 0] = fmaf(s0, inv, sv.x) + bf0;
      out[(size_t)n * 2 + 1] = fmaf(s1, inv, sv.y) + bf1;
    }
  }
}

extern "C" void kernel_launch(void* const* d_in, const int* in_sizes, int n_in,
                              void* d_out, int out_size, void* d_ws,
                              size_t ws_size, hipStream_t stream) {
  const float* x   = (const float*)d_in[0];
  const int*   ei  = (const int*)d_in[1];
  const float* Wl1 = (const float*)d_in[2];
  const float* bl1 = (const float*)d_in[3];
  const float* Wr1 = (const float*)d_in[4];
  const float* Wl2 = (const float*)d_in[5];
  const float* bl2 = (const float*)d_in[6];
  const float* Wr2 = (const float*)d_in[7];
  const float* Wc  = (const float*)d_in[8];
  const float* bc  = (const float*)d_in[9];
  float* out = (float*)d_out;

  int nE = in_sizes[1] / 2;
  const int* src = ei;
  const int* dst = ei + nE;

  // Workspace (~33 MB): r1b bf16[N*64] (aliased by pairs uint2[E] during CSR
  // build; transform runs after passD) | t1 bf16[N*64] | g2,s2 f2[N] |
  // A2/B2/bf | wcat bf16[8192] | degI,rowstart [N] | gcnt | csum | adj[E]
  unsigned short* r1b = (unsigned short*)d_ws;
  uint2* pairs = (uint2*)d_ws;  // alias: dead before transform writes r1b
  unsigned short* t1 = r1b + (size_t)N_NODES * D;
  float2* g2 = (float2*)(t1 + (size_t)N_NODES * D);
  float2* s2 = g2 + N_NODES;
  float* A2 = (float*)(s2 + N_NODES);
  float* B2 = A2 + 128;
  float* bfv = B2 + 128;
  unsigned short* wcat = (unsigned short*)(bfv + 4);
  int* degI = (int*)(wcat + 8192);
  int* rowstart = degI + N_NODES;
  int* gcnt = rowstart + N_NODES;
  int* csum = gcnt + GCNT_N;
  int* adj = csum + 1024;

  int ec = (nE + NBLK_A - 1) / NBLK_A;  // edges per count/place block

  passA_count<<<NBLK_A, 256, 0, stream>>>(dst, gcnt, nE, ec);
  gscan_p1<<<NCHUNK, 256, 0, stream>>>(gcnt, csum);
  gscan_p2<<<1, 1024, 0, stream>>>(csum, NCHUNK);
  gscan_p3<<<NCHUNK, 256, 0, stream>>>(gcnt, csum);
  passC_place<<<NBLK_A, 256, 0, stream>>>(src, dst, gcnt, pairs, nE, ec);
  passD_csr<<<NBUCK, 256, 0, stream>>>(pairs, gcnt, rowstart, degI, adj, nE);

  wfold_kernel<<<1, 128, 0, stream>>>(Wc, Wl2, Wr2, bl2, bc, A2, B2, bfv);
  wprep_kernel<<<32, 256, 0, stream>>>(Wl1, Wr1, wcat);
  transform_mfma<<<512, 256, 0, stream>>>(x, wcat, bl1, t1, r1b);
  gather1_kernel<<<1024, 512, 0, stream>>>(rowstart, degI, adj, t1, r1b, A2,
                                           B2, g2, s2, nE);
  gather2_kernel<<<512, 256, 0, stream>>>(rowstart, degI, adj, g2, s2, bfv,
                                          out, nE);
}